// Round 13
// baseline (165.934 us; speedup 1.0000x reference)
//
#include <hip/hip_runtime.h>
#include <hip/hip_bf16.h>
#include <cstddef>

// ---------------- problem constants (match reference) ----------------
constexpr int N      = 50000;
constexpr int E      = 1600000;
constexpr int NFEAT  = 256;
constexpr float SLOPE = 0.2f;
constexpr float L1d  = 0.5f;
constexpr float L2d  = 0.5f;

// ---------------- counting-sort CSR parameters ----------------
constexpr int BSHIFT = 7;                         // 128 nodes per bucket
constexpr int NBUK   = (N + 127) >> BSHIFT;       // 391 buckets
constexpr int EPB    = 4096;                      // edges per block (P1/P2)
constexpr int NBLK   = (E + EPB - 1) / EPB;       // 391 blocks
constexpr int CAP    = 5120;                      // LDS stage capacity

// ---------------- workspace layout (units of 4 bytes) ----------------
constexpr size_t al64(size_t x) { return (x + 63) & ~size_t(63); }
constexpr size_t W_OFFS  = 0;                            // int[N+1]
constexpr size_t W_CSR   = W_OFFS  + al64(N + 1);        // int[E]
constexpr size_t W_STAGE = W_CSR   + (size_t)E;          // uint[E]
constexpr size_t W_BHIST = W_STAGE + (size_t)E;          // int[NBLK*NBUK]
constexpr size_t W_TOT   = W_BHIST + al64((size_t)NBLK * NBUK);  // int[NBUK]
constexpr size_t W_BBASE = W_TOT   + al64(NBUK);         // int[NBUK+1]
constexpr size_t W_H1B   = W_BBASE + al64(NBUK + 1);     // bf16[N*64] -> N*32 words
constexpr size_t W_S1B   = W_H1B   + (size_t)N * 32;     // bf16[N*8]  -> N*4
constexpr size_t W_D1    = W_S1B   + (size_t)N * 4;      // f32[N*8]
constexpr size_t W_SIDE1 = W_D1    + (size_t)N * 8;      // f32[N*8]
constexpr size_t W_HFB   = W_SIDE1 + (size_t)N * 8;      // bf16[N*64] -> N*32 words
constexpr size_t W_H2B   = W_HFB   + (size_t)N * 32;     // bf16[N*16] -> N*8
constexpr size_t W_SIDE2 = W_H2B   + (size_t)N * 8;      // f32[N*16]
constexpr size_t W_S2B   = W_SIDE2 + (size_t)N * 16;     // bf16[N] -> N/2
constexpr size_t W_D2    = W_S2B   + al64(N / 2);        // f32[N]

typedef short bf16x8 __attribute__((ext_vector_type(8)));
typedef float f32x4  __attribute__((ext_vector_type(4)));

__device__ inline short f2bf(float f) {
    unsigned u = __builtin_bit_cast(unsigned, f);
    u += 0x7FFF + ((u >> 16) & 1);          // RNE
    return (short)(u >> 16);
}

__device__ inline float bfu2f(unsigned short u) {
    return __builtin_bit_cast(float, (unsigned)u << 16);
}

// =================== CSR build: two-level counting sort ===================

__global__ __launch_bounds__(256) void p1_hist_kernel(const int* __restrict__ ei,
                                                      int* __restrict__ bhist) {
    __shared__ int hist[NBUK];
    int tid = threadIdx.x;
    for (int j = tid; j < NBUK; j += 256) hist[j] = 0;
    __syncthreads();
    int base = blockIdx.x * EPB;
    int end = base + EPB; if (end > E) end = E;
    for (int i = base + tid; i < end; i += 256) {
        int d = ei[E + i];
        atomicAdd(&hist[d >> BSHIFT], 1);
    }
    __syncthreads();
    for (int j = tid; j < NBUK; j += 256) bhist[(size_t)blockIdx.x * NBUK + j] = hist[j];
}

__global__ __launch_bounds__(512) void s1_scan_kernel(int* __restrict__ bhist,
                                                      int* __restrict__ tot) {
    __shared__ int sd[512];
    int tid = threadIdx.x;
    int b = blockIdx.x;
    int v = (tid < NBLK) ? bhist[(size_t)tid * NBUK + b] : 0;
    sd[tid] = v;
    __syncthreads();
    for (int off = 1; off < 512; off <<= 1) {
        int t = (tid >= off) ? sd[tid - off] : 0;
        __syncthreads();
        sd[tid] += t;
        __syncthreads();
    }
    if (tid < NBLK) bhist[(size_t)tid * NBUK + b] = sd[tid] - v;
    if (tid == 511) tot[b] = sd[511];
}

__global__ __launch_bounds__(512) void s2_scan_kernel(const int* __restrict__ tot,
                                                      int* __restrict__ bbase,
                                                      int* __restrict__ offs) {
    __shared__ int sd[512];
    int tid = threadIdx.x;
    int v = (tid < NBUK) ? tot[tid] : 0;
    sd[tid] = v;
    __syncthreads();
    for (int off = 1; off < 512; off <<= 1) {
        int t = (tid >= off) ? sd[tid - off] : 0;
        __syncthreads();
        sd[tid] += t;
        __syncthreads();
    }
    if (tid < NBUK) bbase[tid] = sd[tid] - v;
    if (tid == 0) { bbase[NBUK] = E; offs[N] = E; }
}

__global__ __launch_bounds__(256) void p2_stage_kernel(const int* __restrict__ ei,
                                                       const int* __restrict__ bhist,
                                                       const int* __restrict__ bbase,
                                                       unsigned int* __restrict__ stage) {
    __shared__ int cur[NBUK];
    int tid = threadIdx.x;
    for (int j = tid; j < NBUK; j += 256)
        cur[j] = bbase[j] + bhist[(size_t)blockIdx.x * NBUK + j];
    __syncthreads();
    int base = blockIdx.x * EPB;
    int end = base + EPB; if (end > E) end = E;
    for (int i = base + tid; i < end; i += 256) {
        int s = ei[i];
        int d = ei[E + i];
        int b = d >> BSHIFT;
        int pos = atomicAdd(&cur[b], 1);
        stage[pos] = ((unsigned int)(d & 127) << 24) | (unsigned int)s;
    }
}

__global__ __launch_bounds__(256) void p3_fine_kernel(const unsigned int* __restrict__ stage,
                                                      const int* __restrict__ bbase,
                                                      int* __restrict__ offs,
                                                      int* __restrict__ csr) {
    __shared__ unsigned int sstage[CAP];
    __shared__ int hist[128];
    __shared__ int scn[128];
    __shared__ int cur[128];
    int tid = threadIdx.x;
    int b = blockIdx.x;
    int ebase = bbase[b], eend = bbase[b + 1];
    int cnt = eend - ebase;
    if (tid < 128) hist[tid] = 0;
    __syncthreads();
    for (int i = tid; i < cnt; i += 256) {
        unsigned int p = stage[ebase + i];
        if (i < CAP) sstage[i] = p;
        atomicAdd(&hist[p >> 24], 1);
    }
    __syncthreads();
    if (tid < 128) scn[tid] = hist[tid];
    __syncthreads();
    for (int off = 1; off < 128; off <<= 1) {
        int t = (tid < 128 && tid >= off) ? scn[tid - off] : 0;
        __syncthreads();
        if (tid < 128) scn[tid] += t;
        __syncthreads();
    }
    if (tid < 128) {
        int excl = scn[tid] - hist[tid];
        cur[tid] = excl;
        int v = (b << BSHIFT) + tid;
        if (v < N) offs[v] = ebase + excl;
    }
    __syncthreads();
    for (int i = tid; i < cnt; i += 256) {
        unsigned int p = (i < CAP) ? sstage[i] : stage[ebase + i];
        int dloc = (int)(p >> 24);
        int s = (int)(p & 0xFFFFFFu);
        int r = atomicAdd(&cur[dloc], 1);
        csr[ebase + r] = s;
    }
}

// ---------------- GEMM1 (MFMA bf16): [h1b | side1] = x @ [W1 | fc1W] ------------
__global__ __launch_bounds__(256) void gemm1_kernel(const float* __restrict__ x,
                                                    const float* __restrict__ W1,
                                                    const float* __restrict__ fc1W,
                                                    const float* __restrict__ fc1b,
                                                    short* __restrict__ h1b,
                                                    float* __restrict__ side1) {
    __shared__ bf16x8 wfrag[2560];   // 8 kt * 5 nt * 64 lanes * 16B = 40 KB
    int tid = threadIdx.x;

    for (int s = tid; s < 2560; s += 256) {
        int l = s & 63;
        int t = s >> 6;           // kt*5 + nt
        int nt = t % 5, kt = t / 5;
        int col = nt * 16 + (l & 15);
        int kbase = kt * 32 + (l >> 4) * 8;
        bf16x8 v;
#pragma unroll
        for (int j = 0; j < 8; ++j) {
            float f = 0.f;
            if (col < 64)      f = W1[(size_t)(kbase + j) * 64 + col];
            else if (col < 72) f = fc1W[(size_t)(kbase + j) * 8 + (col - 64)];
            v[j] = f2bf(f);
        }
        wfrag[s] = v;
    }
    __syncthreads();

    int w = tid >> 6;       // wave 0..3
    int l = tid & 63;
    int row0 = blockIdx.x * 64;
    int arow = row0 + w * 16 + (l & 15);
    if (arow >= N) arow = N - 1;
    const float* ap = x + (size_t)arow * NFEAT + ((l >> 4) * 8);

    f32x4 acc[5];
#pragma unroll
    for (int nt = 0; nt < 5; ++nt) acc[nt] = (f32x4){0.f, 0.f, 0.f, 0.f};

#pragma unroll
    for (int kt = 0; kt < 8; ++kt) {
        float4 alo = *reinterpret_cast<const float4*>(ap + kt * 32);
        float4 ahi = *reinterpret_cast<const float4*>(ap + kt * 32 + 4);
        bf16x8 af;
        af[0] = f2bf(alo.x); af[1] = f2bf(alo.y); af[2] = f2bf(alo.z); af[3] = f2bf(alo.w);
        af[4] = f2bf(ahi.x); af[5] = f2bf(ahi.y); af[6] = f2bf(ahi.z); af[7] = f2bf(ahi.w);
#pragma unroll
        for (int nt = 0; nt < 5; ++nt) {
            acc[nt] = __builtin_amdgcn_mfma_f32_16x16x32_bf16(
                af, wfrag[(kt * 5 + nt) * 64 + l], acc[nt], 0, 0, 0);
        }
    }

    int cbase = l & 15;
    int rbase = row0 + w * 16 + (l >> 4) * 4;
#pragma unroll
    for (int nt = 0; nt < 4; ++nt) {
#pragma unroll
        for (int r = 0; r < 4; ++r) {
            int row = rbase + r;
            if (row < N) h1b[(size_t)row * 64 + nt * 16 + cbase] = f2bf(acc[nt][r]);
        }
    }
    if (cbase < 8) {
        float bb = fc1b[cbase];
#pragma unroll
        for (int r = 0; r < 4; ++r) {
            int row = rbase + r;
            if (row < N) side1[(size_t)row * 8 + cbase] = acc[4][r] + bb;
        }
    }
}

// ---------------- alpha1: s1b/d1 per node per head ----------------
__global__ __launch_bounds__(256) void alpha1_kernel(const __hip_bfloat16* __restrict__ h1b,
                                                     const float* __restrict__ a1s,
                                                     const float* __restrict__ a1d,
                                                     __hip_bfloat16* __restrict__ s1b,
                                                     float* __restrict__ d1) {
    int wave = threadIdx.x >> 6;
    int lane = threadIdx.x & 63;
    int v = blockIdx.x * 4 + wave;
    if (v >= N) return;
    float hv = __bfloat162float(h1b[(size_t)v * 64 + lane]);
    float sa = hv * a1s[lane];
    float sd = hv * a1d[lane];
#pragma unroll
    for (int off = 1; off < 8; off <<= 1) {
        sa += __shfl_xor(sa, off, 64);
        sd += __shfl_xor(sd, off, 64);
    }
    if ((lane & 7) == 0) {
        s1b[v * 8 + (lane >> 3)] = __float2bfloat16(sa);
        d1[v * 8 + (lane >> 3)] = sd;
    }
}

// ---------------- layer-1 aggregation v7: full/tail split -----------------------
// Wave per dst node. Attention phase in (edge j=lane>>3, head hh=lane&7) layout
// (1 exp covers 8 heads x 8 edges); multiply phase in channel layout with SGPR
// src bases (readlane) + shfl broadcast. Full groups: no clamps/masks. One
// masked tail group. 2-deep ping-pong pipeline (consume-before-reload).
__global__ __launch_bounds__(256) void agg1_kernel(const int* __restrict__ offs,
                                                   const int* __restrict__ csr,
                                                   const unsigned short* __restrict__ h1u,
                                                   const unsigned short* __restrict__ s1u,
                                                   const float* __restrict__ d1,
                                                   const float* __restrict__ side1,
                                                   const float* __restrict__ b1,
                                                   short* __restrict__ hfb) {
    int wave = threadIdx.x >> 6;
    int lane = threadIdx.x & 63;
    int v = blockIdx.x * 4 + wave;
    if (v >= N) return;
    int j  = lane >> 3;   // edge slot (attention phase)
    int hh = lane & 7;    // head (attention phase)
    int hc = lane >> 3;   // head of this channel (multiply phase)

    float dv_att = d1[v * 8 + hh];
    float dv_ch  = __shfl(dv_att, hc, 64);

    // self loop (channel layout)
    float e0 = bfu2f(s1u[v * 8 + hc]) + dv_ch;
    e0 = fmaxf(e0, SLOPE * e0);
    float ex0 = __expf(e0);
    float acc = ex0 * bfu2f(h1u[(size_t)v * 64 + lane]);
    float den0 = ex0;
    float den_att = 0.f;

    int beg = offs[v], end = offs[v + 1];
    int deg = end - beg;
    int ngf = deg >> 3;      // full groups (no clamps, no masks)
    int rem = deg & 7;
    const int* cb = csr + beg;

    unsigned short hA[8], hB[8];
    int sA = 0, sB = 0;
    float svA = 0.f, svB = 0.f;

#define LOADH(s8, h)                                                        \
    do {                                                                     \
        int sj0 = __builtin_amdgcn_readlane(s8, 0);                          \
        int sj1 = __builtin_amdgcn_readlane(s8, 8);                          \
        int sj2 = __builtin_amdgcn_readlane(s8, 16);                         \
        int sj3 = __builtin_amdgcn_readlane(s8, 24);                         \
        int sj4 = __builtin_amdgcn_readlane(s8, 32);                         \
        int sj5 = __builtin_amdgcn_readlane(s8, 40);                         \
        int sj6 = __builtin_amdgcn_readlane(s8, 48);                         \
        int sj7 = __builtin_amdgcn_readlane(s8, 56);                         \
        h[0] = h1u[((size_t)sj0 << 6) + lane];                               \
        h[1] = h1u[((size_t)sj1 << 6) + lane];                               \
        h[2] = h1u[((size_t)sj2 << 6) + lane];                               \
        h[3] = h1u[((size_t)sj3 << 6) + lane];                               \
        h[4] = h1u[((size_t)sj4 << 6) + lane];                               \
        h[5] = h1u[((size_t)sj5 << 6) + lane];                               \
        h[6] = h1u[((size_t)sj6 << 6) + lane];                               \
        h[7] = h1u[((size_t)sj7 << 6) + lane];                               \
    } while (0)

#define COMPF(sv, h)                                                         \
    do {                                                                     \
        float a = (sv) + dv_att;                                             \
        a = fmaxf(a, SLOPE * a);                                             \
        float xv = __expf(a);                                                \
        den_att += xv;                                                       \
        _Pragma("unroll")                                                    \
        for (int jj = 0; jj < 8; ++jj) {                                     \
            float xj = __shfl(xv, jj * 8 + hc, 64);                          \
            acc += xj * bfu2f(h[jj]);                                        \
        }                                                                    \
    } while (0)

    if (ngf > 0) {
        sA = cb[j];
        svA = bfu2f(s1u[sA * 8 + hh]);
        LOADH(sA, hA);
        if (ngf > 1) sB = cb[8 + j];
    }

    int g = 0;
    for (; g + 1 < ngf; g += 2) {
        svB = bfu2f(s1u[sB * 8 + hh]);
        LOADH(sB, hB);
        int sC = (g + 2 < ngf) ? cb[(g + 2) * 8 + j] : 0;
        COMPF(svA, hA);                // A consumed before reload
        sA = sC;
        if (g + 2 < ngf) {
            svA = bfu2f(s1u[sA * 8 + hh]);
            LOADH(sA, hA);
        }
        int sD = (g + 3 < ngf) ? cb[(g + 3) * 8 + j] : 0;
        COMPF(svB, hB);
        sB = sD;
    }
    if (g < ngf) COMPF(svA, hA);

    if (rem) {   // single masked tail group
        int idx = beg + ngf * 8 + j;
        idx = idx < end ? idx : end - 1;
        int s8 = csr[idx];
        float a = bfu2f(s1u[s8 * 8 + hh]) + dv_att;
        a = fmaxf(a, SLOPE * a);
        float xv = __expf(a);
        xv = (j < rem) ? xv : 0.f;
        den_att += xv;
        unsigned short ht[8];
        LOADH(s8, ht);
#pragma unroll
        for (int jj = 0; jj < 8; ++jj) {
            float xj = __shfl(xv, jj * 8 + hc, 64);
            acc += xj * bfu2f(ht[jj]);
        }
    }
#undef LOADH
#undef COMPF

    den_att += __shfl_xor(den_att, 8, 64);
    den_att += __shfl_xor(den_att, 16, 64);
    den_att += __shfl_xor(den_att, 32, 64);
    float den = den0 + __shfl(den_att, hc, 64);

    float o = acc / den + b1[lane];
    float z = o - L1d * side1[v * 8 + (lane & 7)];
    hfb[(size_t)v * 64 + lane] = f2bf(z > 0.f ? z : (__expf(z) - 1.f));
}

// ---------------- GEMM2 (MFMA bf16): [h2b | side2] = hfb @ [W2 | fc2W] ----------
__global__ __launch_bounds__(256) void gemm2_kernel(const unsigned short* __restrict__ hfb,
                                                    const float* __restrict__ W2,
                                                    const float* __restrict__ fc2W,
                                                    const float* __restrict__ fc2b,
                                                    short* __restrict__ h2b,
                                                    float* __restrict__ side2) {
    __shared__ bf16x8 wfrag[256];   // 2 kt * 2 nt * 64 lanes * 16B = 4 KB
    int tid = threadIdx.x;

    if (tid < 256) {
        int s = tid;
        int l = s & 63;
        int t = s >> 6;           // kt*2 + nt
        int nt = t & 1, kt = t >> 1;
        int col = nt * 16 + (l & 15);
        int kbase = kt * 32 + (l >> 4) * 8;
        bf16x8 v;
#pragma unroll
        for (int j = 0; j < 8; ++j) {
            float f = (col < 16) ? W2[(size_t)(kbase + j) * 16 + col]
                                 : fc2W[(size_t)(kbase + j) * 16 + (col - 16)];
            v[j] = f2bf(f);
        }
        wfrag[s] = v;
    }
    __syncthreads();

    int w = tid >> 6;
    int l = tid & 63;
    int row0 = blockIdx.x * 64;
    int arow = row0 + w * 16 + (l & 15);
    if (arow >= N) arow = N - 1;
    const unsigned short* ap = hfb + (size_t)arow * 64 + ((l >> 4) * 8);

    f32x4 acc[2];
    acc[0] = (f32x4){0.f, 0.f, 0.f, 0.f};
    acc[1] = (f32x4){0.f, 0.f, 0.f, 0.f};

#pragma unroll
    for (int kt = 0; kt < 2; ++kt) {
        bf16x8 af = *reinterpret_cast<const bf16x8*>(ap + kt * 32);
#pragma unroll
        for (int nt = 0; nt < 2; ++nt) {
            acc[nt] = __builtin_amdgcn_mfma_f32_16x16x32_bf16(
                af, wfrag[(kt * 2 + nt) * 64 + l], acc[nt], 0, 0, 0);
        }
    }

    int cbase = l & 15;
    int rbase = row0 + w * 16 + (l >> 4) * 4;
    float bb = fc2b[cbase];
#pragma unroll
    for (int r = 0; r < 4; ++r) {
        int row = rbase + r;
        if (row < N) {
            h2b[(size_t)row * 16 + cbase] = f2bf(acc[0][r]);
            side2[(size_t)row * 16 + cbase] = acc[1][r] + bb;
        }
    }
}

// ---------------- alpha2: s2b/d2 per node ----------------
__global__ __launch_bounds__(256) void alpha2_kernel(const __hip_bfloat16* __restrict__ h2b,
                                                     const float* __restrict__ a2s,
                                                     const float* __restrict__ a2d,
                                                     __hip_bfloat16* __restrict__ s2b,
                                                     float* __restrict__ d2) {
    int wave = threadIdx.x >> 6;
    int lane = threadIdx.x & 63;
    int vbase = (blockIdx.x * 4 + wave) * 4;
    int r = lane >> 4;
    int c = lane & 15;
    int v = vbase + r;
    float hv = (v < N) ? __bfloat162float(h2b[(size_t)v * 16 + c]) : 0.f;
    float sa = hv * a2s[c];
    float sd = hv * a2d[c];
#pragma unroll
    for (int off = 1; off < 16; off <<= 1) {
        sa += __shfl_xor(sa, off, 64);
        sd += __shfl_xor(sd, off, 64);
    }
    if (v < N && c == 0) {
        s2b[v] = __float2bfloat16(sa);
        d2[v] = sd;
    }
}

// ---------------- layer-2 aggregation + log_softmax (full/tail split) -----------
__global__ __launch_bounds__(256) void agg2_kernel(const int* __restrict__ offs,
                                                   const int* __restrict__ csr,
                                                   const unsigned short* __restrict__ h2u,
                                                   const unsigned short* __restrict__ s2u,
                                                   const float* __restrict__ d2,
                                                   const float* __restrict__ side2,
                                                   const float* __restrict__ b2,
                                                   float* __restrict__ out) {
    int wave = threadIdx.x >> 6;
    int lane = threadIdx.x & 63;
    int v = blockIdx.x * 4 + wave;
    if (v >= N) return;
    int c = lane & 15;
    int slot = lane >> 4;
    float dv = d2[v];

    float acc = 0.f, den = 0.f;
    if (slot == 0) {
        float e = bfu2f(s2u[v]) + dv;
        e = fmaxf(e, SLOPE * e);
        float ex = __expf(e);
        acc = ex * bfu2f(h2u[(size_t)v * 16 + c]);
        den = ex;
    }
    int beg = offs[v], end = offs[v + 1];
    int deg = end - beg;
    int ngf = deg >> 2;          // full groups: no clamps, no masks
    int rem = deg & 3;
    const int* cb = csr + beg;

    int sA = 0, sB = 0;
    float svA = 0.f, svB = 0.f, hvA = 0.f, hvB = 0.f;
    if (ngf > 0) {
        sA = cb[slot];
        svA = bfu2f(s2u[sA]);
        hvA = bfu2f(h2u[(size_t)sA * 16 + c]);
        if (ngf > 1) sB = cb[4 + slot];
    }
    int g = 0;
    for (; g + 1 < ngf; g += 2) {
        svB = bfu2f(s2u[sB]);
        hvB = bfu2f(h2u[(size_t)sB * 16 + c]);
        int sC = (g + 2 < ngf) ? cb[(g + 2) * 4 + slot] : 0;
        {   // group g (A): svA/hvA consumed before reload
            float a = svA + dv;
            a = fmaxf(a, SLOPE * a);
            float x = __expf(a);
            acc += x * hvA;
            den += x;
        }
        sA = sC;
        if (g + 2 < ngf) {
            svA = bfu2f(s2u[sA]);
            hvA = bfu2f(h2u[(size_t)sA * 16 + c]);
        }
        int sD = (g + 3 < ngf) ? cb[(g + 3) * 4 + slot] : 0;
        {   // group g+1 (B)
            float a = svB + dv;
            a = fmaxf(a, SLOPE * a);
            float x = __expf(a);
            acc += x * hvB;
            den += x;
        }
        sB = sD;
    }
    if (g < ngf) {
        float a = svA + dv;
        a = fmaxf(a, SLOPE * a);
        float x = __expf(a);
        acc += x * hvA;
        den += x;
    }
    if (rem) {   // single masked tail group
        int idx = beg + ngf * 4 + slot;
        idx = idx < end ? idx : end - 1;
        int s = csr[idx];
        float a = bfu2f(s2u[s]) + dv;
        a = fmaxf(a, SLOPE * a);
        float x = __expf(a);
        x = (slot < rem) ? x : 0.f;
        acc += x * bfu2f(h2u[(size_t)s * 16 + c]);
        den += x;
    }

    acc += __shfl_xor(acc, 16, 64);
    acc += __shfl_xor(acc, 32, 64);
    den += __shfl_xor(den, 16, 64);
    den += __shfl_xor(den, 32, 64);

    float o = acc / den + b2[c];
    float z = o - L2d * side2[(size_t)v * 16 + c];

    float m = z;
#pragma unroll
    for (int off = 1; off < 16; off <<= 1) m = fmaxf(m, __shfl_xor(m, off, 64));
    float ex = __expf(z - m);
    float s = ex;
#pragma unroll
    for (int off = 1; off < 16; off <<= 1) s += __shfl_xor(s, off, 64);
    float lsm = z - m - __logf(s);
    if (slot == 0) out[(size_t)v * 16 + c] = lsm;
}

// ---------------- launch ----------------
extern "C" void kernel_launch(void* const* d_in, const int* in_sizes, int n_in,
                              void* d_out, int out_size, void* d_ws, size_t ws_size,
                              hipStream_t stream) {
    const float* x    = (const float*)d_in[0];
    const int*   ei   = (const int*)d_in[1];
    const float* W1   = (const float*)d_in[2];
    const float* a1s  = (const float*)d_in[3];
    const float* a1d  = (const float*)d_in[4];
    const float* b1   = (const float*)d_in[5];
    const float* W2   = (const float*)d_in[6];
    const float* a2s  = (const float*)d_in[7];
    const float* a2d  = (const float*)d_in[8];
    const float* b2   = (const float*)d_in[9];
    const float* fc1W = (const float*)d_in[10];
    const float* fc1b = (const float*)d_in[11];
    const float* fc2W = (const float*)d_in[12];
    const float* fc2b = (const float*)d_in[13];
    float* out = (float*)d_out;

    int*   wsi = (int*)d_ws;
    float* wsf = (float*)d_ws;
    int*   offs   = wsi + W_OFFS;
    int*   csr    = wsi + W_CSR;
    unsigned int* stage = (unsigned int*)(wsi + W_STAGE);
    int*   bhist  = wsi + W_BHIST;
    int*   tot    = wsi + W_TOT;
    int*   bbase  = wsi + W_BBASE;
    __hip_bfloat16* h1b = (__hip_bfloat16*)(wsf + W_H1B);
    __hip_bfloat16* s1b = (__hip_bfloat16*)(wsf + W_S1B);
    float* d1     = wsf + W_D1;
    float* side1  = wsf + W_SIDE1;
    short* hfb    = (short*)(wsf + W_HFB);
    __hip_bfloat16* h2b = (__hip_bfloat16*)(wsf + W_H2B);
    float* side2  = wsf + W_SIDE2;
    __hip_bfloat16* s2b = (__hip_bfloat16*)(wsf + W_S2B);
    float* d2     = wsf + W_D2;

    // CSR build (no global atomics)
    p1_hist_kernel<<<NBLK, 256, 0, stream>>>(ei, bhist);
    s1_scan_kernel<<<NBUK, 512, 0, stream>>>(bhist, tot);
    s2_scan_kernel<<<1, 512, 0, stream>>>(tot, bbase, offs);
    p2_stage_kernel<<<NBLK, 256, 0, stream>>>(ei, bhist, bbase, stage);
    p3_fine_kernel<<<NBUK, 256, 0, stream>>>(stage, bbase, offs, csr);

    gemm1_kernel<<<(N + 63) / 64, 256, 0, stream>>>(x, W1, fc1W, fc1b,
                                                    (short*)h1b, side1);
    alpha1_kernel<<<(N + 3) / 4, 256, 0, stream>>>(h1b, a1s, a1d, s1b, d1);
    agg1_kernel<<<(N + 3) / 4, 256, 0, stream>>>(offs, csr,
                                                 (const unsigned short*)h1b,
                                                 (const unsigned short*)s1b,
                                                 d1, side1, b1, hfb);

    gemm2_kernel<<<(N + 63) / 64, 256, 0, stream>>>((const unsigned short*)hfb,
                                                    W2, fc2W, fc2b,
                                                    (short*)h2b, side2);
    alpha2_kernel<<<(N + 15) / 16, 256, 0, stream>>>(h2b, a2s, a2d, s2b, d2);
    agg2_kernel<<<(N + 3) / 4, 256, 0, stream>>>(offs, csr,
                                                 (const unsigned short*)h2b,
                                                 (const unsigned short*)s2b,
                                                 d2, side2, b2, out);
}

// Round 14
// 149.579 us; speedup vs baseline: 1.1093x; 1.1093x over previous
//
#include <hip/hip_runtime.h>
#include <hip/hip_bf16.h>
#include <cstddef>

// ---------------- problem constants (match reference) ----------------
constexpr int N      = 50000;
constexpr int E      = 1600000;
constexpr int NFEAT  = 256;
constexpr float SLOPE = 0.2f;
constexpr float L1d  = 0.5f;
constexpr float L2d  = 0.5f;

// ---------------- counting-sort CSR parameters ----------------
constexpr int BSHIFT = 7;                         // 128 nodes per bucket
constexpr int NBUK   = (N + 127) >> BSHIFT;       // 391 buckets
constexpr int EPB    = 4096;                      // edges per block (P1/P2)
constexpr int NBLK   = (E + EPB - 1) / EPB;       // 391 blocks
constexpr int CAP    = 5120;                      // LDS stage capacity

// ---------------- workspace layout (units of 4 bytes) ----------------
constexpr size_t al64(size_t x) { return (x + 63) & ~size_t(63); }
constexpr size_t W_OFFS  = 0;                            // int[N+1]
constexpr size_t W_CSR   = W_OFFS  + al64(N + 1);        // int[E]
constexpr size_t W_STAGE = W_CSR   + (size_t)E;          // uint[E]
constexpr size_t W_BHIST = W_STAGE + (size_t)E;          // int[NBLK*NBUK]
constexpr size_t W_TOT   = W_BHIST + al64((size_t)NBLK * NBUK);  // int[NBUK]
constexpr size_t W_BBASE = W_TOT   + al64(NBUK);         // int[NBUK+1]
constexpr size_t W_H1B   = W_BBASE + al64(NBUK + 1);     // bf16[N*64] -> N*32 words
constexpr size_t W_S1B   = W_H1B   + (size_t)N * 32;     // bf16[N*8]  -> N*4
constexpr size_t W_D1    = W_S1B   + (size_t)N * 4;      // f32[N*8]
constexpr size_t W_SIDE1 = W_D1    + (size_t)N * 8;      // f32[N*8]
constexpr size_t W_HFB   = W_SIDE1 + (size_t)N * 8;      // bf16[N*64] -> N*32 words
constexpr size_t W_H2B   = W_HFB   + (size_t)N * 32;     // bf16[N*16] -> N*8
constexpr size_t W_SIDE2 = W_H2B   + (size_t)N * 8;      // f32[N*16]
constexpr size_t W_S2B   = W_SIDE2 + (size_t)N * 16;     // bf16[N] -> N/2
constexpr size_t W_D2    = W_S2B   + al64(N / 2);        // f32[N]

typedef short bf16x8 __attribute__((ext_vector_type(8)));
typedef float f32x4  __attribute__((ext_vector_type(4)));

__device__ inline short f2bf(float f) {
    unsigned u = __builtin_bit_cast(unsigned, f);
    u += 0x7FFF + ((u >> 16) & 1);          // RNE
    return (short)(u >> 16);
}

__device__ inline float bfu2f(unsigned short u) {
    return __builtin_bit_cast(float, (unsigned)u << 16);
}

// =================== CSR build: two-level counting sort ===================

__global__ __launch_bounds__(256) void p1_hist_kernel(const int* __restrict__ ei,
                                                      int* __restrict__ bhist) {
    __shared__ int hist[NBUK];
    int tid = threadIdx.x;
    for (int j = tid; j < NBUK; j += 256) hist[j] = 0;
    __syncthreads();
    int base = blockIdx.x * EPB;
    int end = base + EPB; if (end > E) end = E;
    for (int i = base + tid; i < end; i += 256) {
        int d = ei[E + i];
        atomicAdd(&hist[d >> BSHIFT], 1);
    }
    __syncthreads();
    for (int j = tid; j < NBUK; j += 256) bhist[(size_t)blockIdx.x * NBUK + j] = hist[j];
}

__global__ __launch_bounds__(512) void s1_scan_kernel(int* __restrict__ bhist,
                                                      int* __restrict__ tot) {
    __shared__ int sd[512];
    int tid = threadIdx.x;
    int b = blockIdx.x;
    int v = (tid < NBLK) ? bhist[(size_t)tid * NBUK + b] : 0;
    sd[tid] = v;
    __syncthreads();
    for (int off = 1; off < 512; off <<= 1) {
        int t = (tid >= off) ? sd[tid - off] : 0;
        __syncthreads();
        sd[tid] += t;
        __syncthreads();
    }
    if (tid < NBLK) bhist[(size_t)tid * NBUK + b] = sd[tid] - v;
    if (tid == 511) tot[b] = sd[511];
}

__global__ __launch_bounds__(512) void s2_scan_kernel(const int* __restrict__ tot,
                                                      int* __restrict__ bbase,
                                                      int* __restrict__ offs) {
    __shared__ int sd[512];
    int tid = threadIdx.x;
    int v = (tid < NBUK) ? tot[tid] : 0;
    sd[tid] = v;
    __syncthreads();
    for (int off = 1; off < 512; off <<= 1) {
        int t = (tid >= off) ? sd[tid - off] : 0;
        __syncthreads();
        sd[tid] += t;
        __syncthreads();
    }
    if (tid < NBUK) bbase[tid] = sd[tid] - v;
    if (tid == 0) { bbase[NBUK] = E; offs[N] = E; }
}

__global__ __launch_bounds__(256) void p2_stage_kernel(const int* __restrict__ ei,
                                                       const int* __restrict__ bhist,
                                                       const int* __restrict__ bbase,
                                                       unsigned int* __restrict__ stage) {
    __shared__ int cur[NBUK];
    int tid = threadIdx.x;
    for (int j = tid; j < NBUK; j += 256)
        cur[j] = bbase[j] + bhist[(size_t)blockIdx.x * NBUK + j];
    __syncthreads();
    int base = blockIdx.x * EPB;
    int end = base + EPB; if (end > E) end = E;
    for (int i = base + tid; i < end; i += 256) {
        int s = ei[i];
        int d = ei[E + i];
        int b = d >> BSHIFT;
        int pos = atomicAdd(&cur[b], 1);
        stage[pos] = ((unsigned int)(d & 127) << 24) | (unsigned int)s;
    }
}

__global__ __launch_bounds__(256) void p3_fine_kernel(const unsigned int* __restrict__ stage,
                                                      const int* __restrict__ bbase,
                                                      int* __restrict__ offs,
                                                      int* __restrict__ csr) {
    __shared__ unsigned int sstage[CAP];
    __shared__ int hist[128];
    __shared__ int scn[128];
    __shared__ int cur[128];
    int tid = threadIdx.x;
    int b = blockIdx.x;
    int ebase = bbase[b], eend = bbase[b + 1];
    int cnt = eend - ebase;
    if (tid < 128) hist[tid] = 0;
    __syncthreads();
    for (int i = tid; i < cnt; i += 256) {
        unsigned int p = stage[ebase + i];
        if (i < CAP) sstage[i] = p;
        atomicAdd(&hist[p >> 24], 1);
    }
    __syncthreads();
    if (tid < 128) scn[tid] = hist[tid];
    __syncthreads();
    for (int off = 1; off < 128; off <<= 1) {
        int t = (tid < 128 && tid >= off) ? scn[tid - off] : 0;
        __syncthreads();
        if (tid < 128) scn[tid] += t;
        __syncthreads();
    }
    if (tid < 128) {
        int excl = scn[tid] - hist[tid];
        cur[tid] = excl;
        int v = (b << BSHIFT) + tid;
        if (v < N) offs[v] = ebase + excl;
    }
    __syncthreads();
    for (int i = tid; i < cnt; i += 256) {
        unsigned int p = (i < CAP) ? sstage[i] : stage[ebase + i];
        int dloc = (int)(p >> 24);
        int s = (int)(p & 0xFFFFFFu);
        int r = atomicAdd(&cur[dloc], 1);
        csr[ebase + r] = s;
    }
}

// ---------------- GEMM1 (MFMA bf16) + fused alpha1 ------------------------------
// [h1b | side1] = x @ [W1 | fc1W]; s1b/d1 computed from fp32 acc in epilogue.
__global__ __launch_bounds__(256) void gemm1_kernel(const float* __restrict__ x,
                                                    const float* __restrict__ W1,
                                                    const float* __restrict__ fc1W,
                                                    const float* __restrict__ fc1b,
                                                    const float* __restrict__ a1s,
                                                    const float* __restrict__ a1d,
                                                    short* __restrict__ h1b,
                                                    float* __restrict__ side1,
                                                    short* __restrict__ s1b,
                                                    float* __restrict__ d1) {
    __shared__ bf16x8 wfrag[2560];   // 8 kt * 5 nt * 64 lanes * 16B = 40 KB
    int tid = threadIdx.x;

    for (int s = tid; s < 2560; s += 256) {
        int l = s & 63;
        int t = s >> 6;           // kt*5 + nt
        int nt = t % 5, kt = t / 5;
        int col = nt * 16 + (l & 15);
        int kbase = kt * 32 + (l >> 4) * 8;
        bf16x8 v;
#pragma unroll
        for (int j = 0; j < 8; ++j) {
            float f = 0.f;
            if (col < 64)      f = W1[(size_t)(kbase + j) * 64 + col];
            else if (col < 72) f = fc1W[(size_t)(kbase + j) * 8 + (col - 64)];
            v[j] = f2bf(f);
        }
        wfrag[s] = v;
    }
    __syncthreads();

    int w = tid >> 6;       // wave 0..3
    int l = tid & 63;
    int row0 = blockIdx.x * 64;
    int arow = row0 + w * 16 + (l & 15);
    if (arow >= N) arow = N - 1;
    const float* ap = x + (size_t)arow * NFEAT + ((l >> 4) * 8);

    f32x4 acc[5];
#pragma unroll
    for (int nt = 0; nt < 5; ++nt) acc[nt] = (f32x4){0.f, 0.f, 0.f, 0.f};

#pragma unroll
    for (int kt = 0; kt < 8; ++kt) {
        float4 alo = *reinterpret_cast<const float4*>(ap + kt * 32);
        float4 ahi = *reinterpret_cast<const float4*>(ap + kt * 32 + 4);
        bf16x8 af;
        af[0] = f2bf(alo.x); af[1] = f2bf(alo.y); af[2] = f2bf(alo.z); af[3] = f2bf(alo.w);
        af[4] = f2bf(ahi.x); af[5] = f2bf(ahi.y); af[6] = f2bf(ahi.z); af[7] = f2bf(ahi.w);
#pragma unroll
        for (int nt = 0; nt < 5; ++nt) {
            acc[nt] = __builtin_amdgcn_mfma_f32_16x16x32_bf16(
                af, wfrag[(kt * 5 + nt) * 64 + l], acc[nt], 0, 0, 0);
        }
    }

    int cbase = l & 15;
    int rbase = row0 + w * 16 + (l >> 4) * 4;
#pragma unroll
    for (int nt = 0; nt < 4; ++nt) {
#pragma unroll
        for (int r = 0; r < 4; ++r) {
            int row = rbase + r;
            if (row < N) h1b[(size_t)row * 64 + nt * 16 + cbase] = f2bf(acc[nt][r]);
        }
    }
    if (cbase < 8) {
        float bb = fc1b[cbase];
#pragma unroll
        for (int r = 0; r < 4; ++r) {
            int row = rbase + r;
            if (row < N) side1[(size_t)row * 8 + cbase] = acc[4][r] + bb;
        }
    }

    // fused alpha1: s1/d1 per (row, head); head = nt*2 + (cbase>>3),
    // reduce over cbase&7 (8 channels of a head live in 8 adjacent lanes).
    float as_[4], ad_[4];
#pragma unroll
    for (int nt = 0; nt < 4; ++nt) {
        as_[nt] = a1s[nt * 16 + cbase];
        ad_[nt] = a1d[nt * 16 + cbase];
    }
#pragma unroll
    for (int r = 0; r < 4; ++r) {
        int row = rbase + r;
#pragma unroll
        for (int nt = 0; nt < 4; ++nt) {
            float sa = acc[nt][r] * as_[nt];
            float sd = acc[nt][r] * ad_[nt];
#pragma unroll
            for (int off = 1; off < 8; off <<= 1) {
                sa += __shfl_xor(sa, off, 64);
                sd += __shfl_xor(sd, off, 64);
            }
            if ((cbase & 7) == 0 && row < N) {
                int h = nt * 2 + (cbase >> 3);
                s1b[(size_t)row * 8 + h] = f2bf(sa);
                d1[(size_t)row * 8 + h] = sd;
            }
        }
    }
}

// ---------------- layer-1 aggregation (R11-best: clamped, unconditional) --------
// Wave per dst node, masked 8-edge groups. Attention phase in (edge j=lane>>3,
// head hh=lane&7) layout (1 exp covers 8 heads x 8 edges); multiply phase in
// channel layout with SGPR src bases (readlane) + shfl broadcast. 2-deep pipeline.
__global__ __launch_bounds__(256) void agg1_kernel(const int* __restrict__ offs,
                                                   const int* __restrict__ csr,
                                                   const unsigned short* __restrict__ h1u,
                                                   const unsigned short* __restrict__ s1u,
                                                   const float* __restrict__ d1,
                                                   const float* __restrict__ side1,
                                                   const float* __restrict__ b1,
                                                   short* __restrict__ hfb) {
    int wave = threadIdx.x >> 6;
    int lane = threadIdx.x & 63;
    int v = blockIdx.x * 4 + wave;
    if (v >= N) return;
    int j  = lane >> 3;   // edge slot (attention phase)
    int hh = lane & 7;    // head (attention phase)
    int hc = lane >> 3;   // head of this channel (multiply phase)

    float dv_att = d1[v * 8 + hh];
    float dv_ch  = __shfl(dv_att, hc, 64);

    // self loop (channel layout)
    float e0 = bfu2f(s1u[v * 8 + hc]) + dv_ch;
    e0 = fmaxf(e0, SLOPE * e0);
    float ex0 = __expf(e0);
    float acc = ex0 * bfu2f(h1u[(size_t)v * 64 + lane]);
    float den0 = ex0;
    float den_att = 0.f;

    int beg = offs[v], end = offs[v + 1];
    int deg = end - beg;
    int ng = (deg + 7) >> 3;

    auto csrg = [&](int g) {
        int idx = beg + g * 8 + j;
        idx = idx < end - 1 ? idx : end - 1;
        idx = idx > 0 ? idx : 0;
        return csr[idx];
    };

    unsigned short hA[8], hB[8];
    int sA = 0, sB = 0;
    float svA = 0.f, svB = 0.f;

#define LOADH(s8, h)                                                        \
    do {                                                                     \
        int sj0 = __builtin_amdgcn_readlane(s8, 0);                          \
        int sj1 = __builtin_amdgcn_readlane(s8, 8);                          \
        int sj2 = __builtin_amdgcn_readlane(s8, 16);                         \
        int sj3 = __builtin_amdgcn_readlane(s8, 24);                         \
        int sj4 = __builtin_amdgcn_readlane(s8, 32);                         \
        int sj5 = __builtin_amdgcn_readlane(s8, 40);                         \
        int sj6 = __builtin_amdgcn_readlane(s8, 48);                         \
        int sj7 = __builtin_amdgcn_readlane(s8, 56);                         \
        h[0] = h1u[((size_t)sj0 << 6) + lane];                               \
        h[1] = h1u[((size_t)sj1 << 6) + lane];                               \
        h[2] = h1u[((size_t)sj2 << 6) + lane];                               \
        h[3] = h1u[((size_t)sj3 << 6) + lane];                               \
        h[4] = h1u[((size_t)sj4 << 6) + lane];                               \
        h[5] = h1u[((size_t)sj5 << 6) + lane];                               \
        h[6] = h1u[((size_t)sj6 << 6) + lane];                               \
        h[7] = h1u[((size_t)sj7 << 6) + lane];                               \
    } while (0)

#define COMP(sv, h, gidx)                                                    \
    do {                                                                     \
        float a = (sv) + dv_att;                                             \
        a = fmaxf(a, SLOPE * a);                                             \
        float xv = __expf(a);                                                \
        xv = (beg + (gidx) * 8 + j < end) ? xv : 0.f;                        \
        den_att += xv;                                                       \
        _Pragma("unroll")                                                    \
        for (int jj = 0; jj < 8; ++jj) {                                     \
            float xj = __shfl(xv, jj * 8 + hc, 64);                          \
            acc += xj * bfu2f(h[jj]);                                        \
        }                                                                    \
    } while (0)

    if (ng > 0) {
        sA = csrg(0);
        svA = bfu2f(s1u[sA * 8 + hh]);
        LOADH(sA, hA);
        sB = csrg(1);
    }

    int g = 0;
    for (; g + 1 < ng; g += 2) {
        svB = bfu2f(s1u[sB * 8 + hh]);
        LOADH(sB, hB);
        int sC = csrg(g + 2);
        COMP(svA, hA, g);
        sA = sC;
        svA = bfu2f(s1u[sA * 8 + hh]);
        LOADH(sA, hA);
        int sD = csrg(g + 3);
        COMP(svB, hB, g + 1);
        sB = sD;
    }
    if (g < ng) COMP(svA, hA, g);
#undef LOADH
#undef COMP

    den_att += __shfl_xor(den_att, 8, 64);
    den_att += __shfl_xor(den_att, 16, 64);
    den_att += __shfl_xor(den_att, 32, 64);
    float den = den0 + __shfl(den_att, hc, 64);

    float o = acc / den + b1[lane];
    float z = o - L1d * side1[v * 8 + (lane & 7)];
    hfb[(size_t)v * 64 + lane] = f2bf(z > 0.f ? z : (__expf(z) - 1.f));
}

// ---------------- GEMM2 (MFMA bf16) + fused alpha2 ------------------------------
__global__ __launch_bounds__(256) void gemm2_kernel(const unsigned short* __restrict__ hfb,
                                                    const float* __restrict__ W2,
                                                    const float* __restrict__ fc2W,
                                                    const float* __restrict__ fc2b,
                                                    const float* __restrict__ a2s,
                                                    const float* __restrict__ a2d,
                                                    short* __restrict__ h2b,
                                                    float* __restrict__ side2,
                                                    short* __restrict__ s2b,
                                                    float* __restrict__ d2) {
    __shared__ bf16x8 wfrag[256];   // 2 kt * 2 nt * 64 lanes * 16B = 4 KB
    int tid = threadIdx.x;

    if (tid < 256) {
        int s = tid;
        int l = s & 63;
        int t = s >> 6;           // kt*2 + nt
        int nt = t & 1, kt = t >> 1;
        int col = nt * 16 + (l & 15);
        int kbase = kt * 32 + (l >> 4) * 8;
        bf16x8 v;
#pragma unroll
        for (int j = 0; j < 8; ++j) {
            float f = (col < 16) ? W2[(size_t)(kbase + j) * 16 + col]
                                 : fc2W[(size_t)(kbase + j) * 16 + (col - 16)];
            v[j] = f2bf(f);
        }
        wfrag[s] = v;
    }
    __syncthreads();

    int w = tid >> 6;
    int l = tid & 63;
    int row0 = blockIdx.x * 64;
    int arow = row0 + w * 16 + (l & 15);
    if (arow >= N) arow = N - 1;
    const unsigned short* ap = hfb + (size_t)arow * 64 + ((l >> 4) * 8);

    f32x4 acc[2];
    acc[0] = (f32x4){0.f, 0.f, 0.f, 0.f};
    acc[1] = (f32x4){0.f, 0.f, 0.f, 0.f};

#pragma unroll
    for (int kt = 0; kt < 2; ++kt) {
        bf16x8 af = *reinterpret_cast<const bf16x8*>(ap + kt * 32);
#pragma unroll
        for (int nt = 0; nt < 2; ++nt) {
            acc[nt] = __builtin_amdgcn_mfma_f32_16x16x32_bf16(
                af, wfrag[(kt * 2 + nt) * 64 + l], acc[nt], 0, 0, 0);
        }
    }

    int cbase = l & 15;
    int rbase = row0 + w * 16 + (l >> 4) * 4;
    float bb = fc2b[cbase];
#pragma unroll
    for (int r = 0; r < 4; ++r) {
        int row = rbase + r;
        if (row < N) {
            h2b[(size_t)row * 16 + cbase] = f2bf(acc[0][r]);
            side2[(size_t)row * 16 + cbase] = acc[1][r] + bb;
        }
    }

    // fused alpha2: s2/d2 per row, reduce over the 16 channels (16-lane group)
    float as2 = a2s[cbase], ad2 = a2d[cbase];
#pragma unroll
    for (int r = 0; r < 4; ++r) {
        int row = rbase + r;
        float sa = acc[0][r] * as2;
        float sd = acc[0][r] * ad2;
#pragma unroll
        for (int off = 1; off < 16; off <<= 1) {
            sa += __shfl_xor(sa, off, 64);
            sd += __shfl_xor(sd, off, 64);
        }
        if (cbase == 0 && row < N) {
            s2b[row] = f2bf(sa);
            d2[row] = sd;
        }
    }
}

// ---------------- layer-2 aggregation + log_softmax (full/tail split) -----------
__global__ __launch_bounds__(256) void agg2_kernel(const int* __restrict__ offs,
                                                   const int* __restrict__ csr,
                                                   const unsigned short* __restrict__ h2u,
                                                   const unsigned short* __restrict__ s2u,
                                                   const float* __restrict__ d2,
                                                   const float* __restrict__ side2,
                                                   const float* __restrict__ b2,
                                                   float* __restrict__ out) {
    int wave = threadIdx.x >> 6;
    int lane = threadIdx.x & 63;
    int v = blockIdx.x * 4 + wave;
    if (v >= N) return;
    int c = lane & 15;
    int slot = lane >> 4;
    float dv = d2[v];

    float acc = 0.f, den = 0.f;
    if (slot == 0) {
        float e = bfu2f(s2u[v]) + dv;
        e = fmaxf(e, SLOPE * e);
        float ex = __expf(e);
        acc = ex * bfu2f(h2u[(size_t)v * 16 + c]);
        den = ex;
    }
    int beg = offs[v], end = offs[v + 1];
    int deg = end - beg;
    int ngf = deg >> 2;          // full groups: no clamps, no masks
    int rem = deg & 3;
    const int* cb = csr + beg;

    int sA = 0, sB = 0;
    float svA = 0.f, svB = 0.f, hvA = 0.f, hvB = 0.f;
    if (ngf > 0) {
        sA = cb[slot];
        svA = bfu2f(s2u[sA]);
        hvA = bfu2f(h2u[(size_t)sA * 16 + c]);
        if (ngf > 1) sB = cb[4 + slot];
    }
    int g = 0;
    for (; g + 1 < ngf; g += 2) {
        svB = bfu2f(s2u[sB]);
        hvB = bfu2f(h2u[(size_t)sB * 16 + c]);
        int sC = (g + 2 < ngf) ? cb[(g + 2) * 4 + slot] : 0;
        {   // group g (A): svA/hvA consumed before reload
            float a = svA + dv;
            a = fmaxf(a, SLOPE * a);
            float x = __expf(a);
            acc += x * hvA;
            den += x;
        }
        sA = sC;
        if (g + 2 < ngf) {
            svA = bfu2f(s2u[sA]);
            hvA = bfu2f(h2u[(size_t)sA * 16 + c]);
        }
        int sD = (g + 3 < ngf) ? cb[(g + 3) * 4 + slot] : 0;
        {   // group g+1 (B)
            float a = svB + dv;
            a = fmaxf(a, SLOPE * a);
            float x = __expf(a);
            acc += x * hvB;
            den += x;
        }
        sB = sD;
    }
    if (g < ngf) {
        float a = svA + dv;
        a = fmaxf(a, SLOPE * a);
        float x = __expf(a);
        acc += x * hvA;
        den += x;
    }
    if (rem) {   // single masked tail group
        int idx = beg + ngf * 4 + slot;
        idx = idx < end ? idx : end - 1;
        int s = csr[idx];
        float a = bfu2f(s2u[s]) + dv;
        a = fmaxf(a, SLOPE * a);
        float x = __expf(a);
        x = (slot < rem) ? x : 0.f;
        acc += x * bfu2f(h2u[(size_t)s * 16 + c]);
        den += x;
    }

    acc += __shfl_xor(acc, 16, 64);
    acc += __shfl_xor(acc, 32, 64);
    den += __shfl_xor(den, 16, 64);
    den += __shfl_xor(den, 32, 64);

    float o = acc / den + b2[c];
    float z = o - L2d * side2[(size_t)v * 16 + c];

    float m = z;
#pragma unroll
    for (int off = 1; off < 16; off <<= 1) m = fmaxf(m, __shfl_xor(m, off, 64));
    float ex = __expf(z - m);
    float s = ex;
#pragma unroll
    for (int off = 1; off < 16; off <<= 1) s += __shfl_xor(s, off, 64);
    float lsm = z - m - __logf(s);
    if (slot == 0) out[(size_t)v * 16 + c] = lsm;
}

// ---------------- launch ----------------
extern "C" void kernel_launch(void* const* d_in, const int* in_sizes, int n_in,
                              void* d_out, int out_size, void* d_ws, size_t ws_size,
                              hipStream_t stream) {
    const float* x    = (const float*)d_in[0];
    const int*   ei   = (const int*)d_in[1];
    const float* W1   = (const float*)d_in[2];
    const float* a1s  = (const float*)d_in[3];
    const float* a1d  = (const float*)d_in[4];
    const float* b1   = (const float*)d_in[5];
    const float* W2   = (const float*)d_in[6];
    const float* a2s  = (const float*)d_in[7];
    const float* a2d  = (const float*)d_in[8];
    const float* b2   = (const float*)d_in[9];
    const float* fc1W = (const float*)d_in[10];
    const float* fc1b = (const float*)d_in[11];
    const float* fc2W = (const float*)d_in[12];
    const float* fc2b = (const float*)d_in[13];
    float* out = (float*)d_out;

    int*   wsi = (int*)d_ws;
    float* wsf = (float*)d_ws;
    int*   offs   = wsi + W_OFFS;
    int*   csr    = wsi + W_CSR;
    unsigned int* stage = (unsigned int*)(wsi + W_STAGE);
    int*   bhist  = wsi + W_BHIST;
    int*   tot    = wsi + W_TOT;
    int*   bbase  = wsi + W_BBASE;
    short* h1b    = (short*)(wsf + W_H1B);
    short* s1b    = (short*)(wsf + W_S1B);
    float* d1     = wsf + W_D1;
    float* side1  = wsf + W_SIDE1;
    short* hfb    = (short*)(wsf + W_HFB);
    short* h2b    = (short*)(wsf + W_H2B);
    float* side2  = wsf + W_SIDE2;
    short* s2b    = (short*)(wsf + W_S2B);
    float* d2     = wsf + W_D2;

    // CSR build (no global atomics)
    p1_hist_kernel<<<NBLK, 256, 0, stream>>>(ei, bhist);
    s1_scan_kernel<<<NBUK, 512, 0, stream>>>(bhist, tot);
    s2_scan_kernel<<<1, 512, 0, stream>>>(tot, bbase, offs);
    p2_stage_kernel<<<NBLK, 256, 0, stream>>>(ei, bhist, bbase, stage);
    p3_fine_kernel<<<NBUK, 256, 0, stream>>>(stage, bbase, offs, csr);

    gemm1_kernel<<<(N + 63) / 64, 256, 0, stream>>>(x, W1, fc1W, fc1b, a1s, a1d,
                                                    h1b, side1, s1b, d1);
    agg1_kernel<<<(N + 3) / 4, 256, 0, stream>>>(offs, csr,
                                                 (const unsigned short*)h1b,
                                                 (const unsigned short*)s1b,
                                                 d1, side1, b1, hfb);

    gemm2_kernel<<<(N + 63) / 64, 256, 0, stream>>>((const unsigned short*)hfb,
                                                    W2, fc2W, fc2b, a2s, a2d,
                                                    h2b, side2, s2b, d2);
    agg2_kernel<<<(N + 3) / 4, 256, 0, stream>>>(offs, csr,
                                                 (const unsigned short*)h2b,
                                                 (const unsigned short*)s2b,
                                                 d2, side2, b2, out);
}

// Round 15
// 145.895 us; speedup vs baseline: 1.1373x; 1.0252x over previous
//
#include <hip/hip_runtime.h>
#include <hip/hip_bf16.h>
#include <cstddef>

// ---------------- problem constants (match reference) ----------------
constexpr int N      = 50000;
constexpr int E      = 1600000;
constexpr int NFEAT  = 256;
constexpr float SLOPE = 0.2f;
constexpr float L1d  = 0.5f;
constexpr float L2d  = 0.5f;

// ---------------- counting-sort CSR parameters ----------------
constexpr int BSHIFT = 7;                         // 128 nodes per bucket
constexpr int NBUK   = (N + 127) >> BSHIFT;       // 391 buckets
constexpr int EPB    = 4096;                      // edges per block (P1/P2)
constexpr int NBLK   = (E + EPB - 1) / EPB;       // 391 blocks
constexpr int CAP    = 5120;                      // LDS stage capacity

// ---------------- workspace layout (units of 4 bytes) ----------------
constexpr size_t al64(size_t x) { return (x + 63) & ~size_t(63); }
constexpr size_t W_OFFS  = 0;                            // int[N+1]
constexpr size_t W_CSR   = W_OFFS  + al64(N + 1);        // int[E]
constexpr size_t W_STAGE = W_CSR   + (size_t)E;          // uint[E]
constexpr size_t W_BHIST = W_STAGE + (size_t)E;          // int[NBLK*NBUK]
constexpr size_t W_TOT   = W_BHIST + al64((size_t)NBLK * NBUK);  // int[NBUK]
constexpr size_t W_BBASE = W_TOT   + al64(NBUK);         // int[NBUK+1]
constexpr size_t W_H1B   = W_BBASE + al64(NBUK + 1);     // bf16[N*64] -> N*32 words
constexpr size_t W_S1B   = W_H1B   + (size_t)N * 32;     // bf16[N*8]  -> N*4
constexpr size_t W_D1    = W_S1B   + (size_t)N * 4;      // f32[N*8]
constexpr size_t W_SIDE1 = W_D1    + (size_t)N * 8;      // f32[N*8]
constexpr size_t W_HFB   = W_SIDE1 + (size_t)N * 8;      // bf16[N*64] -> N*32 words
constexpr size_t W_H2B   = W_HFB   + (size_t)N * 32;     // bf16[N*16] -> N*8
constexpr size_t W_SIDE2 = W_H2B   + (size_t)N * 8;      // f32[N*16]
constexpr size_t W_S2B   = W_SIDE2 + (size_t)N * 16;     // bf16[N] -> N/2
constexpr size_t W_D2    = W_S2B   + al64(N / 2);        // f32[N]

typedef short bf16x8 __attribute__((ext_vector_type(8)));
typedef float f32x4  __attribute__((ext_vector_type(4)));

__device__ inline short f2bf(float f) {
    unsigned u = __builtin_bit_cast(unsigned, f);
    u += 0x7FFF + ((u >> 16) & 1);          // RNE
    return (short)(u >> 16);
}

__device__ inline float bfu2f(unsigned short u) {
    return __builtin_bit_cast(float, (unsigned)u << 16);
}

// =================== CSR build: two-level counting sort ===================

__global__ __launch_bounds__(256) void p1_hist_kernel(const int* __restrict__ ei,
                                                      int* __restrict__ bhist) {
    __shared__ int hist[NBUK];
    int tid = threadIdx.x;
    for (int j = tid; j < NBUK; j += 256) hist[j] = 0;
    __syncthreads();
    int base = blockIdx.x * EPB;
    int end = base + EPB; if (end > E) end = E;
    for (int i = base + tid; i < end; i += 256) {
        int d = ei[E + i];
        atomicAdd(&hist[d >> BSHIFT], 1);
    }
    __syncthreads();
    for (int j = tid; j < NBUK; j += 256) bhist[(size_t)blockIdx.x * NBUK + j] = hist[j];
}

__global__ __launch_bounds__(512) void s1_scan_kernel(int* __restrict__ bhist,
                                                      int* __restrict__ tot) {
    __shared__ int sd[512];
    int tid = threadIdx.x;
    int b = blockIdx.x;
    int v = (tid < NBLK) ? bhist[(size_t)tid * NBUK + b] : 0;
    sd[tid] = v;
    __syncthreads();
    for (int off = 1; off < 512; off <<= 1) {
        int t = (tid >= off) ? sd[tid - off] : 0;
        __syncthreads();
        sd[tid] += t;
        __syncthreads();
    }
    if (tid < NBLK) bhist[(size_t)tid * NBUK + b] = sd[tid] - v;
    if (tid == 511) tot[b] = sd[511];
}

__global__ __launch_bounds__(512) void s2_scan_kernel(const int* __restrict__ tot,
                                                      int* __restrict__ bbase,
                                                      int* __restrict__ offs) {
    __shared__ int sd[512];
    int tid = threadIdx.x;
    int v = (tid < NBUK) ? tot[tid] : 0;
    sd[tid] = v;
    __syncthreads();
    for (int off = 1; off < 512; off <<= 1) {
        int t = (tid >= off) ? sd[tid - off] : 0;
        __syncthreads();
        sd[tid] += t;
        __syncthreads();
    }
    if (tid < NBUK) bbase[tid] = sd[tid] - v;
    if (tid == 0) { bbase[NBUK] = E; offs[N] = E; }
}

__global__ __launch_bounds__(256) void p2_stage_kernel(const int* __restrict__ ei,
                                                       const int* __restrict__ bhist,
                                                       const int* __restrict__ bbase,
                                                       unsigned int* __restrict__ stage) {
    __shared__ int cur[NBUK];
    int tid = threadIdx.x;
    for (int j = tid; j < NBUK; j += 256)
        cur[j] = bbase[j] + bhist[(size_t)blockIdx.x * NBUK + j];
    __syncthreads();
    int base = blockIdx.x * EPB;
    int end = base + EPB; if (end > E) end = E;
    for (int i = base + tid; i < end; i += 256) {
        int s = ei[i];
        int d = ei[E + i];
        int b = d >> BSHIFT;
        int pos = atomicAdd(&cur[b], 1);
        stage[pos] = ((unsigned int)(d & 127) << 24) | (unsigned int)s;
    }
}

__global__ __launch_bounds__(256) void p3_fine_kernel(const unsigned int* __restrict__ stage,
                                                      const int* __restrict__ bbase,
                                                      int* __restrict__ offs,
                                                      int* __restrict__ csr) {
    __shared__ unsigned int sstage[CAP];
    __shared__ int hist[128];
    __shared__ int scn[128];
    __shared__ int cur[128];
    int tid = threadIdx.x;
    int b = blockIdx.x;
    int ebase = bbase[b], eend = bbase[b + 1];
    int cnt = eend - ebase;
    if (tid < 128) hist[tid] = 0;
    __syncthreads();
    for (int i = tid; i < cnt; i += 256) {
        unsigned int p = stage[ebase + i];
        if (i < CAP) sstage[i] = p;
        atomicAdd(&hist[p >> 24], 1);
    }
    __syncthreads();
    if (tid < 128) scn[tid] = hist[tid];
    __syncthreads();
    for (int off = 1; off < 128; off <<= 1) {
        int t = (tid < 128 && tid >= off) ? scn[tid - off] : 0;
        __syncthreads();
        if (tid < 128) scn[tid] += t;
        __syncthreads();
    }
    if (tid < 128) {
        int excl = scn[tid] - hist[tid];
        cur[tid] = excl;
        int v = (b << BSHIFT) + tid;
        if (v < N) offs[v] = ebase + excl;
    }
    __syncthreads();
    for (int i = tid; i < cnt; i += 256) {
        unsigned int p = (i < CAP) ? sstage[i] : stage[ebase + i];
        int dloc = (int)(p >> 24);
        int s = (int)(p & 0xFFFFFFu);
        int r = atomicAdd(&cur[dloc], 1);
        csr[ebase + r] = s;
    }
}

// ---------------- GEMM1 (MFMA bf16) + fused alpha1 ------------------------------
__global__ __launch_bounds__(256) void gemm1_kernel(const float* __restrict__ x,
                                                    const float* __restrict__ W1,
                                                    const float* __restrict__ fc1W,
                                                    const float* __restrict__ fc1b,
                                                    const float* __restrict__ a1s,
                                                    const float* __restrict__ a1d,
                                                    short* __restrict__ h1b,
                                                    float* __restrict__ side1,
                                                    short* __restrict__ s1b,
                                                    float* __restrict__ d1) {
    __shared__ bf16x8 wfrag[2560];   // 8 kt * 5 nt * 64 lanes * 16B = 40 KB
    int tid = threadIdx.x;

    for (int s = tid; s < 2560; s += 256) {
        int l = s & 63;
        int t = s >> 6;           // kt*5 + nt
        int nt = t % 5, kt = t / 5;
        int col = nt * 16 + (l & 15);
        int kbase = kt * 32 + (l >> 4) * 8;
        bf16x8 v;
#pragma unroll
        for (int j = 0; j < 8; ++j) {
            float f = 0.f;
            if (col < 64)      f = W1[(size_t)(kbase + j) * 64 + col];
            else if (col < 72) f = fc1W[(size_t)(kbase + j) * 8 + (col - 64)];
            v[j] = f2bf(f);
        }
        wfrag[s] = v;
    }
    __syncthreads();

    int w = tid >> 6;       // wave 0..3
    int l = tid & 63;
    int row0 = blockIdx.x * 64;
    int arow = row0 + w * 16 + (l & 15);
    if (arow >= N) arow = N - 1;
    const float* ap = x + (size_t)arow * NFEAT + ((l >> 4) * 8);

    f32x4 acc[5];
#pragma unroll
    for (int nt = 0; nt < 5; ++nt) acc[nt] = (f32x4){0.f, 0.f, 0.f, 0.f};

#pragma unroll
    for (int kt = 0; kt < 8; ++kt) {
        float4 alo = *reinterpret_cast<const float4*>(ap + kt * 32);
        float4 ahi = *reinterpret_cast<const float4*>(ap + kt * 32 + 4);
        bf16x8 af;
        af[0] = f2bf(alo.x); af[1] = f2bf(alo.y); af[2] = f2bf(alo.z); af[3] = f2bf(alo.w);
        af[4] = f2bf(ahi.x); af[5] = f2bf(ahi.y); af[6] = f2bf(ahi.z); af[7] = f2bf(ahi.w);
#pragma unroll
        for (int nt = 0; nt < 5; ++nt) {
            acc[nt] = __builtin_amdgcn_mfma_f32_16x16x32_bf16(
                af, wfrag[(kt * 5 + nt) * 64 + l], acc[nt], 0, 0, 0);
        }
    }

    int cbase = l & 15;
    int rbase = row0 + w * 16 + (l >> 4) * 4;
#pragma unroll
    for (int nt = 0; nt < 4; ++nt) {
#pragma unroll
        for (int r = 0; r < 4; ++r) {
            int row = rbase + r;
            if (row < N) h1b[(size_t)row * 64 + nt * 16 + cbase] = f2bf(acc[nt][r]);
        }
    }
    if (cbase < 8) {
        float bb = fc1b[cbase];
#pragma unroll
        for (int r = 0; r < 4; ++r) {
            int row = rbase + r;
            if (row < N) side1[(size_t)row * 8 + cbase] = acc[4][r] + bb;
        }
    }

    // fused alpha1: s1/d1 per (row, head); head = nt*2 + (cbase>>3)
    float as_[4], ad_[4];
#pragma unroll
    for (int nt = 0; nt < 4; ++nt) {
        as_[nt] = a1s[nt * 16 + cbase];
        ad_[nt] = a1d[nt * 16 + cbase];
    }
#pragma unroll
    for (int r = 0; r < 4; ++r) {
        int row = rbase + r;
#pragma unroll
        for (int nt = 0; nt < 4; ++nt) {
            float sa = acc[nt][r] * as_[nt];
            float sd = acc[nt][r] * ad_[nt];
#pragma unroll
            for (int off = 1; off < 8; off <<= 1) {
                sa += __shfl_xor(sa, off, 64);
                sd += __shfl_xor(sd, off, 64);
            }
            if ((cbase & 7) == 0 && row < N) {
                int h = nt * 2 + (cbase >> 3);
                s1b[(size_t)row * 8 + h] = f2bf(sa);
                d1[(size_t)row * 8 + h] = sd;
            }
        }
    }
}

// ---------------- layer-1 aggregation v8: scalar-loaded src groups --------------
// R11 structure, but the 8 wave-uniform src ids per group come from SMEM scalar
// loads (readfirstlane'd base + uniform loop counter) instead of vector-load +
// 8x v_readlane. Value-clamped to [0,N) for tail/overrun safety (contributions
// masked by xv=0).
__global__ __launch_bounds__(256) void agg1_kernel(const int* __restrict__ offs,
                                                   const int* __restrict__ csr,
                                                   const unsigned short* __restrict__ h1u,
                                                   const unsigned short* __restrict__ s1u,
                                                   const float* __restrict__ d1,
                                                   const float* __restrict__ side1,
                                                   const float* __restrict__ b1,
                                                   short* __restrict__ hfb) {
    int wave = threadIdx.x >> 6;
    int lane = threadIdx.x & 63;
    int v = blockIdx.x * 4 + wave;
    if (v >= N) return;
    int j  = lane >> 3;   // edge slot (attention phase)
    int hh = lane & 7;    // head (attention phase)
    int hc = lane >> 3;   // head of this channel (multiply phase)

    float dv_att = d1[v * 8 + hh];
    float dv_ch  = __shfl(dv_att, hc, 64);

    // self loop (channel layout)
    float e0 = bfu2f(s1u[v * 8 + hc]) + dv_ch;
    e0 = fmaxf(e0, SLOPE * e0);
    float ex0 = __expf(e0);
    float acc = ex0 * bfu2f(h1u[(size_t)v * 64 + lane]);
    float den0 = ex0;
    float den_att = 0.f;

    int beg = offs[v], end = offs[v + 1];
    int deg = end - beg;
    int ng = (deg + 7) >> 3;
    int ngU = __builtin_amdgcn_readfirstlane(ng);
    int begU = __builtin_amdgcn_readfirstlane(beg);
    const int* cbU = csr + begU;     // uniform base -> scalar loads

    auto csrg = [&](int g) {
        int idx = beg + g * 8 + j;
        idx = idx < end - 1 ? idx : end - 1;
        idx = idx > 0 ? idx : 0;
        return csr[idx];
    };

    unsigned short hA[8], hB[8];
    int sA = 0, sB = 0;
    float svA = 0.f, svB = 0.f;

#define LOADHS(h, gg)                                                        \
    do {                                                                     \
        int t0 = cbU[(gg) * 8 + 0]; int t1 = cbU[(gg) * 8 + 1];              \
        int t2 = cbU[(gg) * 8 + 2]; int t3 = cbU[(gg) * 8 + 3];              \
        int t4 = cbU[(gg) * 8 + 4]; int t5 = cbU[(gg) * 8 + 5];              \
        int t6 = cbU[(gg) * 8 + 6]; int t7 = cbU[(gg) * 8 + 7];              \
        t0 = ((unsigned)t0 < (unsigned)N) ? t0 : 0;                          \
        t1 = ((unsigned)t1 < (unsigned)N) ? t1 : 0;                          \
        t2 = ((unsigned)t2 < (unsigned)N) ? t2 : 0;                          \
        t3 = ((unsigned)t3 < (unsigned)N) ? t3 : 0;                          \
        t4 = ((unsigned)t4 < (unsigned)N) ? t4 : 0;                          \
        t5 = ((unsigned)t5 < (unsigned)N) ? t5 : 0;                          \
        t6 = ((unsigned)t6 < (unsigned)N) ? t6 : 0;                          \
        t7 = ((unsigned)t7 < (unsigned)N) ? t7 : 0;                          \
        h[0] = h1u[((size_t)t0 << 6) + lane];                                \
        h[1] = h1u[((size_t)t1 << 6) + lane];                                \
        h[2] = h1u[((size_t)t2 << 6) + lane];                                \
        h[3] = h1u[((size_t)t3 << 6) + lane];                                \
        h[4] = h1u[((size_t)t4 << 6) + lane];                                \
        h[5] = h1u[((size_t)t5 << 6) + lane];                                \
        h[6] = h1u[((size_t)t6 << 6) + lane];                                \
        h[7] = h1u[((size_t)t7 << 6) + lane];                                \
    } while (0)

#define COMP(sv, h, gidx)                                                    \
    do {                                                                     \
        float a = (sv) + dv_att;                                             \
        a = fmaxf(a, SLOPE * a);                                             \
        float xv = __expf(a);                                                \
        xv = (beg + (gidx) * 8 + j < end) ? xv : 0.f;                        \
        den_att += xv;                                                       \
        _Pragma("unroll")                                                    \
        for (int jj = 0; jj < 8; ++jj) {                                     \
            float xj = __shfl(xv, jj * 8 + hc, 64);                          \
            acc += xj * bfu2f(h[jj]);                                        \
        }                                                                    \
    } while (0)

    if (ngU > 0) {
        sA = csrg(0);
        svA = bfu2f(s1u[sA * 8 + hh]);
        LOADHS(hA, 0);
        sB = csrg(1);
    }

    int g = 0;
    for (; g + 1 < ngU; g += 2) {
        svB = bfu2f(s1u[sB * 8 + hh]);
        LOADHS(hB, g + 1);
        int sC = csrg(g + 2);
        COMP(svA, hA, g);
        sA = sC;
        svA = bfu2f(s1u[sA * 8 + hh]);
        LOADHS(hA, g + 2);
        int sD = csrg(g + 3);
        COMP(svB, hB, g + 1);
        sB = sD;
    }
    if (g < ngU) COMP(svA, hA, g);
#undef LOADHS
#undef COMP

    den_att += __shfl_xor(den_att, 8, 64);
    den_att += __shfl_xor(den_att, 16, 64);
    den_att += __shfl_xor(den_att, 32, 64);
    float den = den0 + __shfl(den_att, hc, 64);

    float o = acc / den + b1[lane];
    float z = o - L1d * side1[v * 8 + (lane & 7)];
    hfb[(size_t)v * 64 + lane] = f2bf(z > 0.f ? z : (__expf(z) - 1.f));
}

// ---------------- GEMM2 (MFMA bf16) + fused alpha2 ------------------------------
__global__ __launch_bounds__(256) void gemm2_kernel(const unsigned short* __restrict__ hfb,
                                                    const float* __restrict__ W2,
                                                    const float* __restrict__ fc2W,
                                                    const float* __restrict__ fc2b,
                                                    const float* __restrict__ a2s,
                                                    const float* __restrict__ a2d,
                                                    short* __restrict__ h2b,
                                                    float* __restrict__ side2,
                                                    short* __restrict__ s2b,
                                                    float* __restrict__ d2) {
    __shared__ bf16x8 wfrag[256];   // 2 kt * 2 nt * 64 lanes * 16B = 4 KB
    int tid = threadIdx.x;

    if (tid < 256) {
        int s = tid;
        int l = s & 63;
        int t = s >> 6;           // kt*2 + nt
        int nt = t & 1, kt = t >> 1;
        int col = nt * 16 + (l & 15);
        int kbase = kt * 32 + (l >> 4) * 8;
        bf16x8 v;
#pragma unroll
        for (int j = 0; j < 8; ++j) {
            float f = (col < 16) ? W2[(size_t)(kbase + j) * 16 + col]
                                 : fc2W[(size_t)(kbase + j) * 16 + (col - 16)];
            v[j] = f2bf(f);
        }
        wfrag[s] = v;
    }
    __syncthreads();

    int w = tid >> 6;
    int l = tid & 63;
    int row0 = blockIdx.x * 64;
    int arow = row0 + w * 16 + (l & 15);
    if (arow >= N) arow = N - 1;
    const unsigned short* ap = hfb + (size_t)arow * 64 + ((l >> 4) * 8);

    f32x4 acc[2];
    acc[0] = (f32x4){0.f, 0.f, 0.f, 0.f};
    acc[1] = (f32x4){0.f, 0.f, 0.f, 0.f};

#pragma unroll
    for (int kt = 0; kt < 2; ++kt) {
        bf16x8 af = *reinterpret_cast<const bf16x8*>(ap + kt * 32);
#pragma unroll
        for (int nt = 0; nt < 2; ++nt) {
            acc[nt] = __builtin_amdgcn_mfma_f32_16x16x32_bf16(
                af, wfrag[(kt * 2 + nt) * 64 + l], acc[nt], 0, 0, 0);
        }
    }

    int cbase = l & 15;
    int rbase = row0 + w * 16 + (l >> 4) * 4;
    float bb = fc2b[cbase];
#pragma unroll
    for (int r = 0; r < 4; ++r) {
        int row = rbase + r;
        if (row < N) {
            h2b[(size_t)row * 16 + cbase] = f2bf(acc[0][r]);
            side2[(size_t)row * 16 + cbase] = acc[1][r] + bb;
        }
    }

    // fused alpha2: s2/d2 per row, reduce over the 16 channels
    float as2 = a2s[cbase], ad2 = a2d[cbase];
#pragma unroll
    for (int r = 0; r < 4; ++r) {
        int row = rbase + r;
        float sa = acc[0][r] * as2;
        float sd = acc[0][r] * ad2;
#pragma unroll
        for (int off = 1; off < 16; off <<= 1) {
            sa += __shfl_xor(sa, off, 64);
            sd += __shfl_xor(sd, off, 64);
        }
        if (cbase == 0 && row < N) {
            s2b[row] = f2bf(sa);
            d2[row] = sd;
        }
    }
}

// ---------------- layer-2 aggregation + log_softmax (full/tail split) -----------
__global__ __launch_bounds__(256) void agg2_kernel(const int* __restrict__ offs,
                                                   const int* __restrict__ csr,
                                                   const unsigned short* __restrict__ h2u,
                                                   const unsigned short* __restrict__ s2u,
                                                   const float* __restrict__ d2,
                                                   const float* __restrict__ side2,
                                                   const float* __restrict__ b2,
                                                   float* __restrict__ out) {
    int wave = threadIdx.x >> 6;
    int lane = threadIdx.x & 63;
    int v = blockIdx.x * 4 + wave;
    if (v >= N) return;
    int c = lane & 15;
    int slot = lane >> 4;
    float dv = d2[v];

    float acc = 0.f, den = 0.f;
    if (slot == 0) {
        float e = bfu2f(s2u[v]) + dv;
        e = fmaxf(e, SLOPE * e);
        float ex = __expf(e);
        acc = ex * bfu2f(h2u[(size_t)v * 16 + c]);
        den = ex;
    }
    int beg = offs[v], end = offs[v + 1];
    int deg = end - beg;
    int ngf = deg >> 2;          // full groups: no clamps, no masks
    int rem = deg & 3;
    const int* cb = csr + beg;

    int sA = 0, sB = 0;
    float svA = 0.f, svB = 0.f, hvA = 0.f, hvB = 0.f;
    if (ngf > 0) {
        sA = cb[slot];
        svA = bfu2f(s2u[sA]);
        hvA = bfu2f(h2u[(size_t)sA * 16 + c]);
        if (ngf > 1) sB = cb[4 + slot];
    }
    int g = 0;
    for (; g + 1 < ngf; g += 2) {
        svB = bfu2f(s2u[sB]);
        hvB = bfu2f(h2u[(size_t)sB * 16 + c]);
        int sC = (g + 2 < ngf) ? cb[(g + 2) * 4 + slot] : 0;
        {   // group g (A): svA/hvA consumed before reload
            float a = svA + dv;
            a = fmaxf(a, SLOPE * a);
            float x = __expf(a);
            acc += x * hvA;
            den += x;
        }
        sA = sC;
        if (g + 2 < ngf) {
            svA = bfu2f(s2u[sA]);
            hvA = bfu2f(h2u[(size_t)sA * 16 + c]);
        }
        int sD = (g + 3 < ngf) ? cb[(g + 3) * 4 + slot] : 0;
        {   // group g+1 (B)
            float a = svB + dv;
            a = fmaxf(a, SLOPE * a);
            float x = __expf(a);
            acc += x * hvB;
            den += x;
        }
        sB = sD;
    }
    if (g < ngf) {
        float a = svA + dv;
        a = fmaxf(a, SLOPE * a);
        float x = __expf(a);
        acc += x * hvA;
        den += x;
    }
    if (rem) {   // single masked tail group
        int idx = beg + ngf * 4 + slot;
        idx = idx < end ? idx : end - 1;
        int s = csr[idx];
        float a = bfu2f(s2u[s]) + dv;
        a = fmaxf(a, SLOPE * a);
        float x = __expf(a);
        x = (slot < rem) ? x : 0.f;
        acc += x * bfu2f(h2u[(size_t)s * 16 + c]);
        den += x;
    }

    acc += __shfl_xor(acc, 16, 64);
    acc += __shfl_xor(acc, 32, 64);
    den += __shfl_xor(den, 16, 64);
    den += __shfl_xor(den, 32, 64);

    float o = acc / den + b2[c];
    float z = o - L2d * side2[(size_t)v * 16 + c];

    float m = z;
#pragma unroll
    for (int off = 1; off < 16; off <<= 1) m = fmaxf(m, __shfl_xor(m, off, 64));
    float ex = __expf(z - m);
    float s = ex;
#pragma unroll
    for (int off = 1; off < 16; off <<= 1) s += __shfl_xor(s, off, 64);
    float lsm = z - m - __logf(s);
    if (slot == 0) out[(size_t)v * 16 + c] = lsm;
}

// ---------------- launch ----------------
extern "C" void kernel_launch(void* const* d_in, const int* in_sizes, int n_in,
                              void* d_out, int out_size, void* d_ws, size_t ws_size,
                              hipStream_t stream) {
    const float* x    = (const float*)d_in[0];
    const int*   ei   = (const int*)d_in[1];
    const float* W1   = (const float*)d_in[2];
    const float* a1s  = (const float*)d_in[3];
    const float* a1d  = (const float*)d_in[4];
    const float* b1   = (const float*)d_in[5];
    const float* W2   = (const float*)d_in[6];
    const float* a2s  = (const float*)d_in[7];
    const float* a2d  = (const float*)d_in[8];
    const float* b2   = (const float*)d_in[9];
    const float* fc1W = (const float*)d_in[10];
    const float* fc1b = (const float*)d_in[11];
    const float* fc2W = (const float*)d_in[12];
    const float* fc2b = (const float*)d_in[13];
    float* out = (float*)d_out;

    int*   wsi = (int*)d_ws;
    float* wsf = (float*)d_ws;
    int*   offs   = wsi + W_OFFS;
    int*   csr    = wsi + W_CSR;
    unsigned int* stage = (unsigned int*)(wsi + W_STAGE);
    int*   bhist  = wsi + W_BHIST;
    int*   tot    = wsi + W_TOT;
    int*   bbase  = wsi + W_BBASE;
    short* h1b    = (short*)(wsf + W_H1B);
    short* s1b    = (short*)(wsf + W_S1B);
    float* d1     = wsf + W_D1;
    float* side1  = wsf + W_SIDE1;
    short* hfb    = (short*)(wsf + W_HFB);
    short* h2b    = (short*)(wsf + W_H2B);
    float* side2  = wsf + W_SIDE2;
    short* s2b    = (short*)(wsf + W_S2B);
    float* d2     = wsf + W_D2;

    // CSR build (no global atomics)
    p1_hist_kernel<<<NBLK, 256, 0, stream>>>(ei, bhist);
    s1_scan_kernel<<<NBUK, 512, 0, stream>>>(bhist, tot);
    s2_scan_kernel<<<1, 512, 0, stream>>>(tot, bbase, offs);
    p2_stage_kernel<<<NBLK, 256, 0, stream>>>(ei, bhist, bbase, stage);
    p3_fine_kernel<<<NBUK, 256, 0, stream>>>(stage, bbase, offs, csr);

    gemm1_kernel<<<(N + 63) / 64, 256, 0, stream>>>(x, W1, fc1W, fc1b, a1s, a1d,
                                                    h1b, side1, s1b, d1);
    agg1_kernel<<<(N + 3) / 4, 256, 0, stream>>>(offs, csr,
                                                 (const unsigned short*)h1b,
                                                 (const unsigned short*)s1b,
                                                 d1, side1, b1, hfb);

    gemm2_kernel<<<(N + 63) / 64, 256, 0, stream>>>((const unsigned short*)hfb,
                                                    W2, fc2W, fc2b, a2s, a2d,
                                                    h2b, side2, s2b, d2);
    agg2_kernel<<<(N + 3) / 4, 256, 0, stream>>>(offs, csr,
                                                 (const unsigned short*)h2b,
                                                 (const unsigned short*)s2b,
                                                 d2, side2, b2, out);
}

// Round 16
// 141.588 us; speedup vs baseline: 1.1719x; 1.0304x over previous
//
#include <hip/hip_runtime.h>
#include <hip/hip_bf16.h>
#include <cstddef>

// ---------------- problem constants (match reference) ----------------
constexpr int N      = 50000;
constexpr int E      = 1600000;
constexpr int NFEAT  = 256;
constexpr float SLOPE = 0.2f;
constexpr float L1d  = 0.5f;
constexpr float L2d  = 0.5f;

// ---------------- counting-sort CSR parameters ----------------
constexpr int BSHIFT = 7;                         // 128 nodes per bucket
constexpr int NBUK   = (N + 127) >> BSHIFT;       // 391 buckets
constexpr int EPB    = 4096;                      // edges per block (P1/P2)
constexpr int NBLK   = (E + EPB - 1) / EPB;       // 391 blocks
constexpr int CAP    = 5120;                      // LDS stage capacity

// ---------------- workspace layout (units of 4 bytes) ----------------
constexpr size_t al64(size_t x) { return (x + 63) & ~size_t(63); }
constexpr size_t W_OFFS  = 0;                            // int[N+1]
constexpr size_t W_CSR   = W_OFFS  + al64(N + 1);        // int[E]
constexpr size_t W_STAGE = W_CSR   + (size_t)E;          // uint[E]
constexpr size_t W_BHIST = W_STAGE + (size_t)E;          // int[NBLK*NBUK]
constexpr size_t W_TOT   = W_BHIST + al64((size_t)NBLK * NBUK);  // int[NBUK]
constexpr size_t W_BBASE = W_TOT   + al64(NBUK);         // int[NBUK+1]
constexpr size_t W_H1B   = W_BBASE + al64(NBUK + 1);     // bf16[N*64] -> N*32 words
constexpr size_t W_S1B   = W_H1B   + (size_t)N * 32;     // bf16[N*8]  -> N*4
constexpr size_t W_D1    = W_S1B   + (size_t)N * 4;      // f32[N*8]
constexpr size_t W_SIDE1 = W_D1    + (size_t)N * 8;      // f32[N*8]
constexpr size_t W_HFB   = W_SIDE1 + (size_t)N * 8;      // bf16[N*64] -> N*32 words
constexpr size_t W_H2B   = W_HFB   + (size_t)N * 32;     // bf16[N*16] -> N*8
constexpr size_t W_SIDE2 = W_H2B   + (size_t)N * 8;      // f32[N*16]
constexpr size_t W_S2B   = W_SIDE2 + (size_t)N * 16;     // bf16[N] -> N/2
constexpr size_t W_D2    = W_S2B   + al64(N / 2);        // f32[N]

typedef short bf16x8 __attribute__((ext_vector_type(8)));
typedef float f32x4  __attribute__((ext_vector_type(4)));

__device__ inline short f2bf(float f) {
    unsigned u = __builtin_bit_cast(unsigned, f);
    u += 0x7FFF + ((u >> 16) & 1);          // RNE
    return (short)(u >> 16);
}

__device__ inline float bfu2f(unsigned short u) {
    return __builtin_bit_cast(float, (unsigned)u << 16);
}

// =================== CSR build: two-level counting sort ===================

__global__ __launch_bounds__(256) void p1_hist_kernel(const int* __restrict__ ei,
                                                      int* __restrict__ bhist) {
    __shared__ int hist[NBUK];
    int tid = threadIdx.x;
    for (int j = tid; j < NBUK; j += 256) hist[j] = 0;
    __syncthreads();
    int base = blockIdx.x * EPB;
    int end = base + EPB; if (end > E) end = E;
    for (int i = base + tid; i < end; i += 256) {
        int d = ei[E + i];
        atomicAdd(&hist[d >> BSHIFT], 1);
    }
    __syncthreads();
    for (int j = tid; j < NBUK; j += 256) bhist[(size_t)blockIdx.x * NBUK + j] = hist[j];
}

__global__ __launch_bounds__(512) void s1_scan_kernel(int* __restrict__ bhist,
                                                      int* __restrict__ tot) {
    __shared__ int sd[512];
    int tid = threadIdx.x;
    int b = blockIdx.x;
    int v = (tid < NBLK) ? bhist[(size_t)tid * NBUK + b] : 0;
    sd[tid] = v;
    __syncthreads();
    for (int off = 1; off < 512; off <<= 1) {
        int t = (tid >= off) ? sd[tid - off] : 0;
        __syncthreads();
        sd[tid] += t;
        __syncthreads();
    }
    if (tid < NBLK) bhist[(size_t)tid * NBUK + b] = sd[tid] - v;
    if (tid == 511) tot[b] = sd[511];
}

__global__ __launch_bounds__(512) void s2_scan_kernel(const int* __restrict__ tot,
                                                      int* __restrict__ bbase,
                                                      int* __restrict__ offs) {
    __shared__ int sd[512];
    int tid = threadIdx.x;
    int v = (tid < NBUK) ? tot[tid] : 0;
    sd[tid] = v;
    __syncthreads();
    for (int off = 1; off < 512; off <<= 1) {
        int t = (tid >= off) ? sd[tid - off] : 0;
        __syncthreads();
        sd[tid] += t;
        __syncthreads();
    }
    if (tid < NBUK) bbase[tid] = sd[tid] - v;
    if (tid == 0) { bbase[NBUK] = E; offs[N] = E; }
}

__global__ __launch_bounds__(256) void p2_stage_kernel(const int* __restrict__ ei,
                                                       const int* __restrict__ bhist,
                                                       const int* __restrict__ bbase,
                                                       unsigned int* __restrict__ stage) {
    __shared__ int cur[NBUK];
    int tid = threadIdx.x;
    for (int j = tid; j < NBUK; j += 256)
        cur[j] = bbase[j] + bhist[(size_t)blockIdx.x * NBUK + j];
    __syncthreads();
    int base = blockIdx.x * EPB;
    int end = base + EPB; if (end > E) end = E;
    for (int i = base + tid; i < end; i += 256) {
        int s = ei[i];
        int d = ei[E + i];
        int b = d >> BSHIFT;
        int pos = atomicAdd(&cur[b], 1);
        stage[pos] = ((unsigned int)(d & 127) << 24) | (unsigned int)s;
    }
}

__global__ __launch_bounds__(256) void p3_fine_kernel(const unsigned int* __restrict__ stage,
                                                      const int* __restrict__ bbase,
                                                      int* __restrict__ offs,
                                                      int* __restrict__ csr) {
    __shared__ unsigned int sstage[CAP];
    __shared__ int hist[128];
    __shared__ int scn[128];
    __shared__ int cur[128];
    int tid = threadIdx.x;
    int b = blockIdx.x;
    int ebase = bbase[b], eend = bbase[b + 1];
    int cnt = eend - ebase;
    if (tid < 128) hist[tid] = 0;
    __syncthreads();
    for (int i = tid; i < cnt; i += 256) {
        unsigned int p = stage[ebase + i];
        if (i < CAP) sstage[i] = p;
        atomicAdd(&hist[p >> 24], 1);
    }
    __syncthreads();
    if (tid < 128) scn[tid] = hist[tid];
    __syncthreads();
    for (int off = 1; off < 128; off <<= 1) {
        int t = (tid < 128 && tid >= off) ? scn[tid - off] : 0;
        __syncthreads();
        if (tid < 128) scn[tid] += t;
        __syncthreads();
    }
    if (tid < 128) {
        int excl = scn[tid] - hist[tid];
        cur[tid] = excl;
        int v = (b << BSHIFT) + tid;
        if (v < N) offs[v] = ebase + excl;
    }
    __syncthreads();
    for (int i = tid; i < cnt; i += 256) {
        unsigned int p = (i < CAP) ? sstage[i] : stage[ebase + i];
        int dloc = (int)(p >> 24);
        int s = (int)(p & 0xFFFFFFu);
        int r = atomicAdd(&cur[dloc], 1);
        csr[ebase + r] = s;
    }
}

// ---------------- GEMM1 (MFMA bf16) + fused alpha1 ------------------------------
__global__ __launch_bounds__(256) void gemm1_kernel(const float* __restrict__ x,
                                                    const float* __restrict__ W1,
                                                    const float* __restrict__ fc1W,
                                                    const float* __restrict__ fc1b,
                                                    const float* __restrict__ a1s,
                                                    const float* __restrict__ a1d,
                                                    short* __restrict__ h1b,
                                                    float* __restrict__ side1,
                                                    short* __restrict__ s1b,
                                                    float* __restrict__ d1) {
    __shared__ bf16x8 wfrag[2560];   // 8 kt * 5 nt * 64 lanes * 16B = 40 KB
    int tid = threadIdx.x;

    for (int s = tid; s < 2560; s += 256) {
        int l = s & 63;
        int t = s >> 6;           // kt*5 + nt
        int nt = t % 5, kt = t / 5;
        int col = nt * 16 + (l & 15);
        int kbase = kt * 32 + (l >> 4) * 8;
        bf16x8 v;
#pragma unroll
        for (int j = 0; j < 8; ++j) {
            float f = 0.f;
            if (col < 64)      f = W1[(size_t)(kbase + j) * 64 + col];
            else if (col < 72) f = fc1W[(size_t)(kbase + j) * 8 + (col - 64)];
            v[j] = f2bf(f);
        }
        wfrag[s] = v;
    }
    __syncthreads();

    int w = tid >> 6;       // wave 0..3
    int l = tid & 63;
    int row0 = blockIdx.x * 64;
    int arow = row0 + w * 16 + (l & 15);
    if (arow >= N) arow = N - 1;
    const float* ap = x + (size_t)arow * NFEAT + ((l >> 4) * 8);

    f32x4 acc[5];
#pragma unroll
    for (int nt = 0; nt < 5; ++nt) acc[nt] = (f32x4){0.f, 0.f, 0.f, 0.f};

#pragma unroll
    for (int kt = 0; kt < 8; ++kt) {
        float4 alo = *reinterpret_cast<const float4*>(ap + kt * 32);
        float4 ahi = *reinterpret_cast<const float4*>(ap + kt * 32 + 4);
        bf16x8 af;
        af[0] = f2bf(alo.x); af[1] = f2bf(alo.y); af[2] = f2bf(alo.z); af[3] = f2bf(alo.w);
        af[4] = f2bf(ahi.x); af[5] = f2bf(ahi.y); af[6] = f2bf(ahi.z); af[7] = f2bf(ahi.w);
#pragma unroll
        for (int nt = 0; nt < 5; ++nt) {
            acc[nt] = __builtin_amdgcn_mfma_f32_16x16x32_bf16(
                af, wfrag[(kt * 5 + nt) * 64 + l], acc[nt], 0, 0, 0);
        }
    }

    int cbase = l & 15;
    int rbase = row0 + w * 16 + (l >> 4) * 4;
#pragma unroll
    for (int nt = 0; nt < 4; ++nt) {
#pragma unroll
        for (int r = 0; r < 4; ++r) {
            int row = rbase + r;
            if (row < N) h1b[(size_t)row * 64 + nt * 16 + cbase] = f2bf(acc[nt][r]);
        }
    }
    if (cbase < 8) {
        float bb = fc1b[cbase];
#pragma unroll
        for (int r = 0; r < 4; ++r) {
            int row = rbase + r;
            if (row < N) side1[(size_t)row * 8 + cbase] = acc[4][r] + bb;
        }
    }

    // fused alpha1: s1/d1 per (row, head); head = nt*2 + (cbase>>3)
    float as_[4], ad_[4];
#pragma unroll
    for (int nt = 0; nt < 4; ++nt) {
        as_[nt] = a1s[nt * 16 + cbase];
        ad_[nt] = a1d[nt * 16 + cbase];
    }
#pragma unroll
    for (int r = 0; r < 4; ++r) {
        int row = rbase + r;
#pragma unroll
        for (int nt = 0; nt < 4; ++nt) {
            float sa = acc[nt][r] * as_[nt];
            float sd = acc[nt][r] * ad_[nt];
#pragma unroll
            for (int off = 1; off < 8; off <<= 1) {
                sa += __shfl_xor(sa, off, 64);
                sd += __shfl_xor(sd, off, 64);
            }
            if ((cbase & 7) == 0 && row < N) {
                int h = nt * 2 + (cbase >> 3);
                s1b[(size_t)row * 8 + h] = f2bf(sa);
                d1[(size_t)row * 8 + h] = sd;
            }
        }
    }
}

// ---------------- layer-1 aggregation v8: scalar-loaded src groups --------------
__global__ __launch_bounds__(256) void agg1_kernel(const int* __restrict__ offs,
                                                   const int* __restrict__ csr,
                                                   const unsigned short* __restrict__ h1u,
                                                   const unsigned short* __restrict__ s1u,
                                                   const float* __restrict__ d1,
                                                   const float* __restrict__ side1,
                                                   const float* __restrict__ b1,
                                                   short* __restrict__ hfb) {
    int wave = threadIdx.x >> 6;
    int lane = threadIdx.x & 63;
    int v = blockIdx.x * 4 + wave;
    if (v >= N) return;
    int j  = lane >> 3;   // edge slot (attention phase)
    int hh = lane & 7;    // head (attention phase)
    int hc = lane >> 3;   // head of this channel (multiply phase)

    float dv_att = d1[v * 8 + hh];
    float dv_ch  = __shfl(dv_att, hc, 64);

    // self loop (channel layout)
    float e0 = bfu2f(s1u[v * 8 + hc]) + dv_ch;
    e0 = fmaxf(e0, SLOPE * e0);
    float ex0 = __expf(e0);
    float acc = ex0 * bfu2f(h1u[(size_t)v * 64 + lane]);
    float den0 = ex0;
    float den_att = 0.f;

    int beg = offs[v], end = offs[v + 1];
    int deg = end - beg;
    int ng = (deg + 7) >> 3;
    int ngU = __builtin_amdgcn_readfirstlane(ng);
    int begU = __builtin_amdgcn_readfirstlane(beg);
    const int* cbU = csr + begU;     // uniform base -> scalar loads

    auto csrg = [&](int g) {
        int idx = beg + g * 8 + j;
        idx = idx < end - 1 ? idx : end - 1;
        idx = idx > 0 ? idx : 0;
        return csr[idx];
    };

    unsigned short hA[8], hB[8];
    int sA = 0, sB = 0;
    float svA = 0.f, svB = 0.f;

#define LOADHS(h, gg)                                                        \
    do {                                                                     \
        int t0 = cbU[(gg) * 8 + 0]; int t1 = cbU[(gg) * 8 + 1];              \
        int t2 = cbU[(gg) * 8 + 2]; int t3 = cbU[(gg) * 8 + 3];              \
        int t4 = cbU[(gg) * 8 + 4]; int t5 = cbU[(gg) * 8 + 5];              \
        int t6 = cbU[(gg) * 8 + 6]; int t7 = cbU[(gg) * 8 + 7];              \
        t0 = ((unsigned)t0 < (unsigned)N) ? t0 : 0;                          \
        t1 = ((unsigned)t1 < (unsigned)N) ? t1 : 0;                          \
        t2 = ((unsigned)t2 < (unsigned)N) ? t2 : 0;                          \
        t3 = ((unsigned)t3 < (unsigned)N) ? t3 : 0;                          \
        t4 = ((unsigned)t4 < (unsigned)N) ? t4 : 0;                          \
        t5 = ((unsigned)t5 < (unsigned)N) ? t5 : 0;                          \
        t6 = ((unsigned)t6 < (unsigned)N) ? t6 : 0;                          \
        t7 = ((unsigned)t7 < (unsigned)N) ? t7 : 0;                          \
        h[0] = h1u[((size_t)t0 << 6) + lane];                                \
        h[1] = h1u[((size_t)t1 << 6) + lane];                                \
        h[2] = h1u[((size_t)t2 << 6) + lane];                                \
        h[3] = h1u[((size_t)t3 << 6) + lane];                                \
        h[4] = h1u[((size_t)t4 << 6) + lane];                                \
        h[5] = h1u[((size_t)t5 << 6) + lane];                                \
        h[6] = h1u[((size_t)t6 << 6) + lane];                                \
        h[7] = h1u[((size_t)t7 << 6) + lane];                                \
    } while (0)

#define COMP(sv, h, gidx)                                                    \
    do {                                                                     \
        float a = (sv) + dv_att;                                             \
        a = fmaxf(a, SLOPE * a);                                             \
        float xv = __expf(a);                                                \
        xv = (beg + (gidx) * 8 + j < end) ? xv : 0.f;                        \
        den_att += xv;                                                       \
        _Pragma("unroll")                                                    \
        for (int jj = 0; jj < 8; ++jj) {                                     \
            float xj = __shfl(xv, jj * 8 + hc, 64);                          \
            acc += xj * bfu2f(h[jj]);                                        \
        }                                                                    \
    } while (0)

    if (ngU > 0) {
        sA = csrg(0);
        svA = bfu2f(s1u[sA * 8 + hh]);
        LOADHS(hA, 0);
        sB = csrg(1);
    }

    int g = 0;
    for (; g + 1 < ngU; g += 2) {
        svB = bfu2f(s1u[sB * 8 + hh]);
        LOADHS(hB, g + 1);
        int sC = csrg(g + 2);
        COMP(svA, hA, g);
        sA = sC;
        svA = bfu2f(s1u[sA * 8 + hh]);
        LOADHS(hA, g + 2);
        int sD = csrg(g + 3);
        COMP(svB, hB, g + 1);
        sB = sD;
    }
    if (g < ngU) COMP(svA, hA, g);
#undef LOADHS
#undef COMP

    den_att += __shfl_xor(den_att, 8, 64);
    den_att += __shfl_xor(den_att, 16, 64);
    den_att += __shfl_xor(den_att, 32, 64);
    float den = den0 + __shfl(den_att, hc, 64);

    float o = acc / den + b1[lane];
    float z = o - L1d * side1[v * 8 + (lane & 7)];
    hfb[(size_t)v * 64 + lane] = f2bf(z > 0.f ? z : (__expf(z) - 1.f));
}

// ---------------- GEMM2 (MFMA bf16) + fused alpha2 ------------------------------
__global__ __launch_bounds__(256) void gemm2_kernel(const unsigned short* __restrict__ hfb,
                                                    const float* __restrict__ W2,
                                                    const float* __restrict__ fc2W,
                                                    const float* __restrict__ fc2b,
                                                    const float* __restrict__ a2s,
                                                    const float* __restrict__ a2d,
                                                    short* __restrict__ h2b,
                                                    float* __restrict__ side2,
                                                    short* __restrict__ s2b,
                                                    float* __restrict__ d2) {
    __shared__ bf16x8 wfrag[256];   // 2 kt * 2 nt * 64 lanes * 16B = 4 KB
    int tid = threadIdx.x;

    if (tid < 256) {
        int s = tid;
        int l = s & 63;
        int t = s >> 6;           // kt*2 + nt
        int nt = t & 1, kt = t >> 1;
        int col = nt * 16 + (l & 15);
        int kbase = kt * 32 + (l >> 4) * 8;
        bf16x8 v;
#pragma unroll
        for (int j = 0; j < 8; ++j) {
            float f = (col < 16) ? W2[(size_t)(kbase + j) * 16 + col]
                                 : fc2W[(size_t)(kbase + j) * 16 + (col - 16)];
            v[j] = f2bf(f);
        }
        wfrag[s] = v;
    }
    __syncthreads();

    int w = tid >> 6;
    int l = tid & 63;
    int row0 = blockIdx.x * 64;
    int arow = row0 + w * 16 + (l & 15);
    if (arow >= N) arow = N - 1;
    const unsigned short* ap = hfb + (size_t)arow * 64 + ((l >> 4) * 8);

    f32x4 acc[2];
    acc[0] = (f32x4){0.f, 0.f, 0.f, 0.f};
    acc[1] = (f32x4){0.f, 0.f, 0.f, 0.f};

#pragma unroll
    for (int kt = 0; kt < 2; ++kt) {
        bf16x8 af = *reinterpret_cast<const bf16x8*>(ap + kt * 32);
#pragma unroll
        for (int nt = 0; nt < 2; ++nt) {
            acc[nt] = __builtin_amdgcn_mfma_f32_16x16x32_bf16(
                af, wfrag[(kt * 2 + nt) * 64 + l], acc[nt], 0, 0, 0);
        }
    }

    int cbase = l & 15;
    int rbase = row0 + w * 16 + (l >> 4) * 4;
    float bb = fc2b[cbase];
#pragma unroll
    for (int r = 0; r < 4; ++r) {
        int row = rbase + r;
        if (row < N) {
            h2b[(size_t)row * 16 + cbase] = f2bf(acc[0][r]);
            side2[(size_t)row * 16 + cbase] = acc[1][r] + bb;
        }
    }

    // fused alpha2: s2/d2 per row, reduce over the 16 channels
    float as2 = a2s[cbase], ad2 = a2d[cbase];
#pragma unroll
    for (int r = 0; r < 4; ++r) {
        int row = rbase + r;
        float sa = acc[0][r] * as2;
        float sd = acc[0][r] * ad2;
#pragma unroll
        for (int off = 1; off < 16; off <<= 1) {
            sa += __shfl_xor(sa, off, 64);
            sd += __shfl_xor(sd, off, 64);
        }
        if (cbase == 0 && row < N) {
            s2b[row] = f2bf(sa);
            d2[row] = sd;
        }
    }
}

// ---------------- layer-2 aggregation v6 + log_softmax: 8-edge groups -----------
// Each slot (lane>>4) owns tail positions slot and 4+slot of an 8-edge group ->
// 6 loads in flight per stage, 2-deep ping-pong, ~4 serial groups per node.
__global__ __launch_bounds__(256) void agg2_kernel(const int* __restrict__ offs,
                                                   const int* __restrict__ csr,
                                                   const unsigned short* __restrict__ h2u,
                                                   const unsigned short* __restrict__ s2u,
                                                   const float* __restrict__ d2,
                                                   const float* __restrict__ side2,
                                                   const float* __restrict__ b2,
                                                   float* __restrict__ out) {
    int wave = threadIdx.x >> 6;
    int lane = threadIdx.x & 63;
    int v = blockIdx.x * 4 + wave;
    if (v >= N) return;
    int c = lane & 15;
    int slot = lane >> 4;
    float dv = d2[v];

    float acc = 0.f, den = 0.f;
    if (slot == 0) {
        float e = bfu2f(s2u[v]) + dv;
        e = fmaxf(e, SLOPE * e);
        float ex = __expf(e);
        acc = ex * bfu2f(h2u[(size_t)v * 16 + c]);
        den = ex;
    }
    int beg = offs[v], end = offs[v + 1];
    int deg = end - beg;
    int ngf = deg >> 3;          // full 8-edge groups: no clamps, no masks
    int rem = deg & 7;
    const int* cb = csr + beg;

    int sA0 = 0, sA1 = 0, sB0 = 0, sB1 = 0;
    float svA0 = 0.f, svA1 = 0.f, hvA0 = 0.f, hvA1 = 0.f;
    float svB0 = 0.f, svB1 = 0.f, hvB0 = 0.f, hvB1 = 0.f;
    if (ngf > 0) {
        sA0 = cb[slot];
        sA1 = cb[4 + slot];
        svA0 = bfu2f(s2u[sA0]);
        svA1 = bfu2f(s2u[sA1]);
        hvA0 = bfu2f(h2u[(size_t)sA0 * 16 + c]);
        hvA1 = bfu2f(h2u[(size_t)sA1 * 16 + c]);
        if (ngf > 1) { sB0 = cb[8 + slot]; sB1 = cb[12 + slot]; }
    }
    int g = 0;
    for (; g + 1 < ngf; g += 2) {
        svB0 = bfu2f(s2u[sB0]);
        svB1 = bfu2f(s2u[sB1]);
        hvB0 = bfu2f(h2u[(size_t)sB0 * 16 + c]);
        hvB1 = bfu2f(h2u[(size_t)sB1 * 16 + c]);
        int sC0 = (g + 2 < ngf) ? cb[(g + 2) * 8 + slot] : 0;
        int sC1 = (g + 2 < ngf) ? cb[(g + 2) * 8 + 4 + slot] : 0;
        {   // group g (A): consumed before reload
            float a0 = svA0 + dv; a0 = fmaxf(a0, SLOPE * a0);
            float a1 = svA1 + dv; a1 = fmaxf(a1, SLOPE * a1);
            float x0 = __expf(a0), x1 = __expf(a1);
            acc += x0 * hvA0 + x1 * hvA1;
            den += x0 + x1;
        }
        sA0 = sC0; sA1 = sC1;
        if (g + 2 < ngf) {
            svA0 = bfu2f(s2u[sA0]);
            svA1 = bfu2f(s2u[sA1]);
            hvA0 = bfu2f(h2u[(size_t)sA0 * 16 + c]);
            hvA1 = bfu2f(h2u[(size_t)sA1 * 16 + c]);
        }
        int sD0 = (g + 3 < ngf) ? cb[(g + 3) * 8 + slot] : 0;
        int sD1 = (g + 3 < ngf) ? cb[(g + 3) * 8 + 4 + slot] : 0;
        {   // group g+1 (B)
            float a0 = svB0 + dv; a0 = fmaxf(a0, SLOPE * a0);
            float a1 = svB1 + dv; a1 = fmaxf(a1, SLOPE * a1);
            float x0 = __expf(a0), x1 = __expf(a1);
            acc += x0 * hvB0 + x1 * hvB1;
            den += x0 + x1;
        }
        sB0 = sD0; sB1 = sD1;
    }
    if (g < ngf) {
        float a0 = svA0 + dv; a0 = fmaxf(a0, SLOPE * a0);
        float a1 = svA1 + dv; a1 = fmaxf(a1, SLOPE * a1);
        float x0 = __expf(a0), x1 = __expf(a1);
        acc += x0 * hvA0 + x1 * hvA1;
        den += x0 + x1;
    }
    if (rem) {   // single masked 8-edge tail group
        int i0 = beg + ngf * 8 + slot;
        int i1 = beg + ngf * 8 + 4 + slot;
        int i0c = i0 < end ? i0 : end - 1;
        int i1c = i1 < end ? i1 : end - 1;
        int s0 = csr[i0c];
        int s1_ = csr[i1c];
        float a0 = bfu2f(s2u[s0]) + dv;  a0 = fmaxf(a0, SLOPE * a0);
        float a1 = bfu2f(s2u[s1_]) + dv; a1 = fmaxf(a1, SLOPE * a1);
        float x0 = __expf(a0), x1 = __expf(a1);
        x0 = (slot < rem) ? x0 : 0.f;
        x1 = (4 + slot < rem) ? x1 : 0.f;
        acc += x0 * bfu2f(h2u[(size_t)s0 * 16 + c]);
        acc += x1 * bfu2f(h2u[(size_t)s1_ * 16 + c]);
        den += x0 + x1;
    }

    acc += __shfl_xor(acc, 16, 64);
    acc += __shfl_xor(acc, 32, 64);
    den += __shfl_xor(den, 16, 64);
    den += __shfl_xor(den, 32, 64);

    float o = acc / den + b2[c];
    float z = o - L2d * side2[(size_t)v * 16 + c];

    float m = z;
#pragma unroll
    for (int off = 1; off < 16; off <<= 1) m = fmaxf(m, __shfl_xor(m, off, 64));
    float ex = __expf(z - m);
    float s = ex;
#pragma unroll
    for (int off = 1; off < 16; off <<= 1) s += __shfl_xor(s, off, 64);
    float lsm = z - m - __logf(s);
    if (slot == 0) out[(size_t)v * 16 + c] = lsm;
}

// ---------------- launch ----------------
extern "C" void kernel_launch(void* const* d_in, const int* in_sizes, int n_in,
                              void* d_out, int out_size, void* d_ws, size_t ws_size,
                              hipStream_t stream) {
    const float* x    = (const float*)d_in[0];
    const int*   ei   = (const int*)d_in[1];
    const float* W1   = (const float*)d_in[2];
    const float* a1s  = (const float*)d_in[3];
    const float* a1d  = (const float*)d_in[4];
    const float* b1   = (const float*)d_in[5];
    const float* W2   = (const float*)d_in[6];
    const float* a2s  = (const float*)d_in[7];
    const float* a2d  = (const float*)d_in[8];
    const float* b2   = (const float*)d_in[9];
    const float* fc1W = (const float*)d_in[10];
    const float* fc1b = (const float*)d_in[11];
    const float* fc2W = (const float*)d_in[12];
    const float* fc2b = (const float*)d_in[13];
    float* out = (float*)d_out;

    int*   wsi = (int*)d_ws;
    float* wsf = (float*)d_ws;
    int*   offs   = wsi + W_OFFS;
    int*   csr    = wsi + W_CSR;
    unsigned int* stage = (unsigned int*)(wsi + W_STAGE);
    int*   bhist  = wsi + W_BHIST;
    int*   tot    = wsi + W_TOT;
    int*   bbase  = wsi + W_BBASE;
    short* h1b    = (short*)(wsf + W_H1B);
    short* s1b    = (short*)(wsf + W_S1B);
    float* d1     = wsf + W_D1;
    float* side1  = wsf + W_SIDE1;
    short* hfb    = (short*)(wsf + W_HFB);
    short* h2b    = (short*)(wsf + W_H2B);
    float* side2  = wsf + W_SIDE2;
    short* s2b    = (short*)(wsf + W_S2B);
    float* d2     = wsf + W_D2;

    // CSR build (no global atomics)
    p1_hist_kernel<<<NBLK, 256, 0, stream>>>(ei, bhist);
    s1_scan_kernel<<<NBUK, 512, 0, stream>>>(bhist, tot);
    s2_scan_kernel<<<1, 512, 0, stream>>>(tot, bbase, offs);
    p2_stage_kernel<<<NBLK, 256, 0, stream>>>(ei, bhist, bbase, stage);
    p3_fine_kernel<<<NBUK, 256, 0, stream>>>(stage, bbase, offs, csr);

    gemm1_kernel<<<(N + 63) / 64, 256, 0, stream>>>(x, W1, fc1W, fc1b, a1s, a1d,
                                                    h1b, side1, s1b, d1);
    agg1_kernel<<<(N + 3) / 4, 256, 0, stream>>>(offs, csr,
                                                 (const unsigned short*)h1b,
                                                 (const unsigned short*)s1b,
                                                 d1, side1, b1, hfb);

    gemm2_kernel<<<(N + 63) / 64, 256, 0, stream>>>((const unsigned short*)hfb,
                                                    W2, fc2W, fc2b, a2s, a2d,
                                                    h2b, side2, s2b, d2);
    agg2_kernel<<<(N + 3) / 4, 256, 0, stream>>>(offs, csr,
                                                 (const unsigned short*)h2b,
                                                 (const unsigned short*)s2b,
                                                 d2, side2, b2, out);
}

// Round 18
// 138.426 us; speedup vs baseline: 1.1987x; 1.0228x over previous
//
#include <hip/hip_runtime.h>
#include <hip/hip_bf16.h>
#include <cstddef>

// ---------------- problem constants (match reference) ----------------
constexpr int N      = 50000;
constexpr int E      = 1600000;
constexpr int NFEAT  = 256;
constexpr float SLOPE = 0.2f;
constexpr float L1d  = 0.5f;
constexpr float L2d  = 0.5f;

// ---------------- counting-sort CSR parameters ----------------
constexpr int BSHIFT = 7;                         // 128 nodes per bucket
constexpr int NBUK   = (N + 127) >> BSHIFT;       // 391 buckets
constexpr int EPB    = 4096;                      // edges per block (P1/P2)
constexpr int NBLK   = (E + EPB - 1) / EPB;       // 391 blocks
constexpr int CAP    = 5120;                      // LDS stage capacity

// ---------------- workspace layout (units of 4 bytes) ----------------
constexpr size_t al64(size_t x) { return (x + 63) & ~size_t(63); }
constexpr size_t W_OFFS  = 0;                            // int[N+1]
constexpr size_t W_CSR   = W_OFFS  + al64(N + 1);        // int[E]
constexpr size_t W_STAGE = W_CSR   + (size_t)E;          // uint[E]
constexpr size_t W_BHIST = W_STAGE + (size_t)E;          // int[NBLK*NBUK]
constexpr size_t W_TOT   = W_BHIST + al64((size_t)NBLK * NBUK);  // int[NBUK]
constexpr size_t W_BBASE = W_TOT   + al64(NBUK);         // int[NBUK+1]
constexpr size_t W_H1B   = W_BBASE + al64(NBUK + 1);     // bf16[N*64] -> N*32 words
constexpr size_t W_S1B   = W_H1B   + (size_t)N * 32;     // bf16[N*8]  -> N*4
constexpr size_t W_D1    = W_S1B   + (size_t)N * 4;      // f32[N*8]
constexpr size_t W_SIDE1 = W_D1    + (size_t)N * 8;      // f32[N*8]
constexpr size_t W_HFB   = W_SIDE1 + (size_t)N * 8;      // bf16[N*64] -> N*32 words
constexpr size_t W_H2B   = W_HFB   + (size_t)N * 32;     // bf16[N*16] -> N*8
constexpr size_t W_SIDE2 = W_H2B   + (size_t)N * 8;      // f32[N*16]
constexpr size_t W_S2B   = W_SIDE2 + (size_t)N * 16;     // bf16[N] -> N/2
constexpr size_t W_D2    = W_S2B   + al64(N / 2);        // f32[N]

typedef short bf16x8 __attribute__((ext_vector_type(8)));
typedef float f32x4  __attribute__((ext_vector_type(4)));
typedef unsigned uintx4 __attribute__((ext_vector_type(4)));

__device__ inline short f2bf(float f) {
    unsigned u = __builtin_bit_cast(unsigned, f);
    u += 0x7FFF + ((u >> 16) & 1);          // RNE
    return (short)(u >> 16);
}

__device__ inline float bfu2f(unsigned short u) {
    return __builtin_bit_cast(float, (unsigned)u << 16);
}

__device__ inline unsigned pkbf(float a, float b) {
    __hip_bfloat162 p = __float22bfloat162_rn(float2{a, b});  // v_cvt_pk_bf16_f32
    unsigned u;
    __builtin_memcpy(&u, &p, 4);
    return u;
}

// =================== CSR build: two-level counting sort ===================

__global__ __launch_bounds__(256) void p1_hist_kernel(const int* __restrict__ ei,
                                                      int* __restrict__ bhist) {
    __shared__ int hist[NBUK];
    int tid = threadIdx.x;
    for (int j = tid; j < NBUK; j += 256) hist[j] = 0;
    __syncthreads();
    int base = blockIdx.x * EPB;
    int cnt = E - base; if (cnt > EPB) cnt = EPB;
    int cnt4 = cnt >> 2;                       // E divisible by 4: exact
    const int4* dp = reinterpret_cast<const int4*>(ei + E + base);
    for (int i = tid; i < cnt4; i += 256) {
        int4 d4 = dp[i];
        atomicAdd(&hist[d4.x >> BSHIFT], 1);
        atomicAdd(&hist[d4.y >> BSHIFT], 1);
        atomicAdd(&hist[d4.z >> BSHIFT], 1);
        atomicAdd(&hist[d4.w >> BSHIFT], 1);
    }
    __syncthreads();
    for (int j = tid; j < NBUK; j += 256) bhist[(size_t)blockIdx.x * NBUK + j] = hist[j];
}

__global__ __launch_bounds__(512) void s1_scan_kernel(int* __restrict__ bhist,
                                                      int* __restrict__ tot) {
    __shared__ int sd[512];
    int tid = threadIdx.x;
    int b = blockIdx.x;
    int v = (tid < NBLK) ? bhist[(size_t)tid * NBUK + b] : 0;
    sd[tid] = v;
    __syncthreads();
    for (int off = 1; off < 512; off <<= 1) {
        int t = (tid >= off) ? sd[tid - off] : 0;
        __syncthreads();
        sd[tid] += t;
        __syncthreads();
    }
    if (tid < NBLK) bhist[(size_t)tid * NBUK + b] = sd[tid] - v;
    if (tid == 511) tot[b] = sd[511];
}

__global__ __launch_bounds__(512) void s2_scan_kernel(const int* __restrict__ tot,
                                                      int* __restrict__ bbase,
                                                      int* __restrict__ offs) {
    __shared__ int sd[512];
    int tid = threadIdx.x;
    int v = (tid < NBUK) ? tot[tid] : 0;
    sd[tid] = v;
    __syncthreads();
    for (int off = 1; off < 512; off <<= 1) {
        int t = (tid >= off) ? sd[tid - off] : 0;
        __syncthreads();
        sd[tid] += t;
        __syncthreads();
    }
    if (tid < NBUK) bbase[tid] = sd[tid] - v;
    if (tid == 0) { bbase[NBUK] = E; offs[N] = E; }
}

__global__ __launch_bounds__(256) void p2_stage_kernel(const int* __restrict__ ei,
                                                       const int* __restrict__ bhist,
                                                       const int* __restrict__ bbase,
                                                       unsigned int* __restrict__ stage) {
    __shared__ int cur[NBUK];
    int tid = threadIdx.x;
    for (int j = tid; j < NBUK; j += 256)
        cur[j] = bbase[j] + bhist[(size_t)blockIdx.x * NBUK + j];
    __syncthreads();
    int base = blockIdx.x * EPB;
    int cnt = E - base; if (cnt > EPB) cnt = EPB;
    int cnt4 = cnt >> 2;
    const int4* sp = reinterpret_cast<const int4*>(ei + base);
    const int4* dp = reinterpret_cast<const int4*>(ei + E + base);
    for (int i = tid; i < cnt4; i += 256) {
        int4 s4 = sp[i];
        int4 d4 = dp[i];
#pragma unroll
        for (int k = 0; k < 4; ++k) {
            int s = (k == 0) ? s4.x : (k == 1) ? s4.y : (k == 2) ? s4.z : s4.w;
            int d = (k == 0) ? d4.x : (k == 1) ? d4.y : (k == 2) ? d4.z : d4.w;
            int b = d >> BSHIFT;
            int pos = atomicAdd(&cur[b], 1);
            stage[pos] = ((unsigned int)(d & 127) << 24) | (unsigned int)s;
        }
    }
}

__global__ __launch_bounds__(256) void p3_fine_kernel(const unsigned int* __restrict__ stage,
                                                      const int* __restrict__ bbase,
                                                      int* __restrict__ offs,
                                                      int* __restrict__ csr) {
    __shared__ unsigned int sstage[CAP];
    __shared__ int hist[128];
    __shared__ int scn[128];
    __shared__ int cur[128];
    int tid = threadIdx.x;
    int b = blockIdx.x;
    int ebase = bbase[b], eend = bbase[b + 1];
    int cnt = eend - ebase;
    if (tid < 128) hist[tid] = 0;
    __syncthreads();
    for (int i = tid; i < cnt; i += 256) {
        unsigned int p = stage[ebase + i];
        if (i < CAP) sstage[i] = p;
        atomicAdd(&hist[p >> 24], 1);
    }
    __syncthreads();
    if (tid < 128) scn[tid] = hist[tid];
    __syncthreads();
    for (int off = 1; off < 128; off <<= 1) {
        int t = (tid < 128 && tid >= off) ? scn[tid - off] : 0;
        __syncthreads();
        if (tid < 128) scn[tid] += t;
        __syncthreads();
    }
    if (tid < 128) {
        int excl = scn[tid] - hist[tid];
        cur[tid] = excl;
        int v = (b << BSHIFT) + tid;
        if (v < N) offs[v] = ebase + excl;
    }
    __syncthreads();
    for (int i = tid; i < cnt; i += 256) {
        unsigned int p = (i < CAP) ? sstage[i] : stage[ebase + i];
        int dloc = (int)(p >> 24);
        int s = (int)(p & 0xFFFFFFu);
        int r = atomicAdd(&cur[dloc], 1);
        csr[ebase + r] = s;
    }
}

// ---------------- GEMM1 (MFMA bf16) + fused alpha1 ------------------------------
__global__ __launch_bounds__(256) void gemm1_kernel(const float* __restrict__ x,
                                                    const float* __restrict__ W1,
                                                    const float* __restrict__ fc1W,
                                                    const float* __restrict__ fc1b,
                                                    const float* __restrict__ a1s,
                                                    const float* __restrict__ a1d,
                                                    short* __restrict__ h1b,
                                                    float* __restrict__ side1,
                                                    short* __restrict__ s1b,
                                                    float* __restrict__ d1) {
    __shared__ bf16x8 wfrag[2560];   // 8 kt * 5 nt * 64 lanes * 16B = 40 KB
    int tid = threadIdx.x;

    for (int s = tid; s < 2560; s += 256) {
        int l = s & 63;
        int t = s >> 6;           // kt*5 + nt
        int nt = t % 5, kt = t / 5;
        int col = nt * 16 + (l & 15);
        int kbase = kt * 32 + (l >> 4) * 8;
        bf16x8 v;
#pragma unroll
        for (int j = 0; j < 8; ++j) {
            float f = 0.f;
            if (col < 64)      f = W1[(size_t)(kbase + j) * 64 + col];
            else if (col < 72) f = fc1W[(size_t)(kbase + j) * 8 + (col - 64)];
            v[j] = f2bf(f);
        }
        wfrag[s] = v;
    }
    __syncthreads();

    int w = tid >> 6;       // wave 0..3
    int l = tid & 63;
    int row0 = blockIdx.x * 64;
    int arow = row0 + w * 16 + (l & 15);
    if (arow >= N) arow = N - 1;
    const float* ap = x + (size_t)arow * NFEAT + ((l >> 4) * 8);

    f32x4 acc[5];
#pragma unroll
    for (int nt = 0; nt < 5; ++nt) acc[nt] = (f32x4){0.f, 0.f, 0.f, 0.f};

#pragma unroll
    for (int kt = 0; kt < 8; ++kt) {
        float4 alo = *reinterpret_cast<const float4*>(ap + kt * 32);
        float4 ahi = *reinterpret_cast<const float4*>(ap + kt * 32 + 4);
        uintx4 u;
        u[0] = pkbf(alo.x, alo.y);
        u[1] = pkbf(alo.z, alo.w);
        u[2] = pkbf(ahi.x, ahi.y);
        u[3] = pkbf(ahi.z, ahi.w);
        bf16x8 af = __builtin_bit_cast(bf16x8, u);
#pragma unroll
        for (int nt = 0; nt < 5; ++nt) {
            acc[nt] = __builtin_amdgcn_mfma_f32_16x16x32_bf16(
                af, wfrag[(kt * 5 + nt) * 64 + l], acc[nt], 0, 0, 0);
        }
    }

    int cbase = l & 15;
    int rbase = row0 + w * 16 + (l >> 4) * 4;
#pragma unroll
    for (int nt = 0; nt < 4; ++nt) {
#pragma unroll
        for (int r = 0; r < 4; ++r) {
            int row = rbase + r;
            if (row < N) h1b[(size_t)row * 64 + nt * 16 + cbase] = f2bf(acc[nt][r]);
        }
    }
    if (cbase < 8) {
        float bb = fc1b[cbase];
#pragma unroll
        for (int r = 0; r < 4; ++r) {
            int row = rbase + r;
            if (row < N) side1[(size_t)row * 8 + cbase] = acc[4][r] + bb;
        }
    }

    // fused alpha1: s1/d1 per (row, head); head = nt*2 + (cbase>>3)
    float as_[4], ad_[4];
#pragma unroll
    for (int nt = 0; nt < 4; ++nt) {
        as_[nt] = a1s[nt * 16 + cbase];
        ad_[nt] = a1d[nt * 16 + cbase];
    }
#pragma unroll
    for (int r = 0; r < 4; ++r) {
        int row = rbase + r;
#pragma unroll
        for (int nt = 0; nt < 4; ++nt) {
            float sa = acc[nt][r] * as_[nt];
            float sd = acc[nt][r] * ad_[nt];
#pragma unroll
            for (int off = 1; off < 8; off <<= 1) {
                sa += __shfl_xor(sa, off, 64);
                sd += __shfl_xor(sd, off, 64);
            }
            if ((cbase & 7) == 0 && row < N) {
                int h = nt * 2 + (cbase >> 3);
                s1b[(size_t)row * 8 + h] = f2bf(sa);
                d1[(size_t)row * 8 + h] = sd;
            }
        }
    }
}

// ---------------- layer-1 aggregation v8: scalar-loaded src groups --------------
__global__ __launch_bounds__(256) void agg1_kernel(const int* __restrict__ offs,
                                                   const int* __restrict__ csr,
                                                   const unsigned short* __restrict__ h1u,
                                                   const unsigned short* __restrict__ s1u,
                                                   const float* __restrict__ d1,
                                                   const float* __restrict__ side1,
                                                   const float* __restrict__ b1,
                                                   short* __restrict__ hfb) {
    int wave = threadIdx.x >> 6;
    int lane = threadIdx.x & 63;
    int v = blockIdx.x * 4 + wave;
    if (v >= N) return;
    int j  = lane >> 3;   // edge slot (attention phase)
    int hh = lane & 7;    // head (attention phase)
    int hc = lane >> 3;   // head of this channel (multiply phase)

    float dv_att = d1[v * 8 + hh];
    float dv_ch  = __shfl(dv_att, hc, 64);

    // self loop (channel layout)
    float e0 = bfu2f(s1u[v * 8 + hc]) + dv_ch;
    e0 = fmaxf(e0, SLOPE * e0);
    float ex0 = __expf(e0);
    float acc = ex0 * bfu2f(h1u[(size_t)v * 64 + lane]);
    float den0 = ex0;
    float den_att = 0.f;

    int beg = offs[v], end = offs[v + 1];
    int deg = end - beg;
    int ng = (deg + 7) >> 3;
    int ngU = __builtin_amdgcn_readfirstlane(ng);
    int begU = __builtin_amdgcn_readfirstlane(beg);
    const int* cbU = csr + begU;     // uniform base -> scalar loads

    auto csrg = [&](int g) {
        int idx = beg + g * 8 + j;
        idx = idx < end - 1 ? idx : end - 1;
        idx = idx > 0 ? idx : 0;
        return csr[idx];
    };

    unsigned short hA[8], hB[8];
    int sA = 0, sB = 0;
    float svA = 0.f, svB = 0.f;

#define LOADHS(h, gg)                                                        \
    do {                                                                     \
        int t0 = cbU[(gg) * 8 + 0]; int t1 = cbU[(gg) * 8 + 1];              \
        int t2 = cbU[(gg) * 8 + 2]; int t3 = cbU[(gg) * 8 + 3];              \
        int t4 = cbU[(gg) * 8 + 4]; int t5 = cbU[(gg) * 8 + 5];              \
        int t6 = cbU[(gg) * 8 + 6]; int t7 = cbU[(gg) * 8 + 7];              \
        t0 = ((unsigned)t0 < (unsigned)N) ? t0 : 0;                          \
        t1 = ((unsigned)t1 < (unsigned)N) ? t1 : 0;                          \
        t2 = ((unsigned)t2 < (unsigned)N) ? t2 : 0;                          \
        t3 = ((unsigned)t3 < (unsigned)N) ? t3 : 0;                          \
        t4 = ((unsigned)t4 < (unsigned)N) ? t4 : 0;                          \
        t5 = ((unsigned)t5 < (unsigned)N) ? t5 : 0;                          \
        t6 = ((unsigned)t6 < (unsigned)N) ? t6 : 0;                          \
        t7 = ((unsigned)t7 < (unsigned)N) ? t7 : 0;                          \
        h[0] = h1u[((size_t)t0 << 6) + lane];                                \
        h[1] = h1u[((size_t)t1 << 6) + lane];                                \
        h[2] = h1u[((size_t)t2 << 6) + lane];                                \
        h[3] = h1u[((size_t)t3 << 6) + lane];                                \
        h[4] = h1u[((size_t)t4 << 6) + lane];                                \
        h[5] = h1u[((size_t)t5 << 6) + lane];                                \
        h[6] = h1u[((size_t)t6 << 6) + lane];                                \
        h[7] = h1u[((size_t)t7 << 6) + lane];                                \
    } while (0)

#define COMP(sv, h, gidx)                                                    \
    do {                                                                     \
        float a = (sv) + dv_att;                                             \
        a = fmaxf(a, SLOPE * a);                                             \
        float xv = __expf(a);                                                \
        xv = (beg + (gidx) * 8 + j < end) ? xv : 0.f;                        \
        den_att += xv;                                                       \
        _Pragma("unroll")                                                    \
        for (int jj = 0; jj < 8; ++jj) {                                     \
            float xj = __shfl(xv, jj * 8 + hc, 64);                          \
            acc += xj * bfu2f(h[jj]);                                        \
        }                                                                    \
    } while (0)

    if (ngU > 0) {
        sA = csrg(0);
        svA = bfu2f(s1u[sA * 8 + hh]);
        LOADHS(hA, 0);
        sB = csrg(1);
    }

    int g = 0;
    for (; g + 1 < ngU; g += 2) {
        svB = bfu2f(s1u[sB * 8 + hh]);
        LOADHS(hB, g + 1);
        int sC = csrg(g + 2);
        COMP(svA, hA, g);
        sA = sC;
        svA = bfu2f(s1u[sA * 8 + hh]);
        LOADHS(hA, g + 2);
        int sD = csrg(g + 3);
        COMP(svB, hB, g + 1);
        sB = sD;
    }
    if (g < ngU) COMP(svA, hA, g);
#undef LOADHS
#undef COMP

    den_att += __shfl_xor(den_att, 8, 64);
    den_att += __shfl_xor(den_att, 16, 64);
    den_att += __shfl_xor(den_att, 32, 64);
    float den = den0 + __shfl(den_att, hc, 64);

    float o = acc / den + b1[lane];
    float z = o - L1d * side1[v * 8 + (lane & 7)];
    hfb[(size_t)v * 64 + lane] = f2bf(z > 0.f ? z : (__expf(z) - 1.f));
}

// ---------------- GEMM2 (MFMA bf16) + fused alpha2 ------------------------------
__global__ __launch_bounds__(256) void gemm2_kernel(const unsigned short* __restrict__ hfb,
                                                    const float* __restrict__ W2,
                                                    const float* __restrict__ fc2W,
                                                    const float* __restrict__ fc2b,
                                                    const float* __restrict__ a2s,
                                                    const float* __restrict__ a2d,
                                                    short* __restrict__ h2b,
                                                    float* __restrict__ side2,
                                                    short* __restrict__ s2b,
                                                    float* __restrict__ d2) {
    __shared__ bf16x8 wfrag[256];   // 2 kt * 2 nt * 64 lanes * 16B = 4 KB
    int tid = threadIdx.x;

    if (tid < 256) {
        int s = tid;
        int l = s & 63;
        int t = s >> 6;           // kt*2 + nt
        int nt = t & 1, kt = t >> 1;
        int col = nt * 16 + (l & 15);
        int kbase = kt * 32 + (l >> 4) * 8;
        bf16x8 v;
#pragma unroll
        for (int j = 0; j < 8; ++j) {
            float f = (col < 16) ? W2[(size_t)(kbase + j) * 16 + col]
                                 : fc2W[(size_t)(kbase + j) * 16 + (col - 16)];
            v[j] = f2bf(f);
        }
        wfrag[s] = v;
    }
    __syncthreads();

    int w = tid >> 6;
    int l = tid & 63;
    int row0 = blockIdx.x * 64;
    int arow = row0 + w * 16 + (l & 15);
    if (arow >= N) arow = N - 1;
    const unsigned short* ap = hfb + (size_t)arow * 64 + ((l >> 4) * 8);

    f32x4 acc[2];
    acc[0] = (f32x4){0.f, 0.f, 0.f, 0.f};
    acc[1] = (f32x4){0.f, 0.f, 0.f, 0.f};

#pragma unroll
    for (int kt = 0; kt < 2; ++kt) {
        bf16x8 af = *reinterpret_cast<const bf16x8*>(ap + kt * 32);
#pragma unroll
        for (int nt = 0; nt < 2; ++nt) {
            acc[nt] = __builtin_amdgcn_mfma_f32_16x16x32_bf16(
                af, wfrag[(kt * 2 + nt) * 64 + l], acc[nt], 0, 0, 0);
        }
    }

    int cbase = l & 15;
    int rbase = row0 + w * 16 + (l >> 4) * 4;
    float bb = fc2b[cbase];
#pragma unroll
    for (int r = 0; r < 4; ++r) {
        int row = rbase + r;
        if (row < N) {
            h2b[(size_t)row * 16 + cbase] = f2bf(acc[0][r]);
            side2[(size_t)row * 16 + cbase] = acc[1][r] + bb;
        }
    }

    // fused alpha2: s2/d2 per row, reduce over the 16 channels
    float as2 = a2s[cbase], ad2 = a2d[cbase];
#pragma unroll
    for (int r = 0; r < 4; ++r) {
        int row = rbase + r;
        float sa = acc[0][r] * as2;
        float sd = acc[0][r] * ad2;
#pragma unroll
        for (int off = 1; off < 16; off <<= 1) {
            sa += __shfl_xor(sa, off, 64);
            sd += __shfl_xor(sd, off, 64);
        }
        if (cbase == 0 && row < N) {
            s2b[row] = f2bf(sa);
            d2[row] = sd;
        }
    }
}

// ---------------- layer-2 aggregation v6 + log_softmax: 8-edge groups -----------
__global__ __launch_bounds__(256) void agg2_kernel(const int* __restrict__ offs,
                                                   const int* __restrict__ csr,
                                                   const unsigned short* __restrict__ h2u,
                                                   const unsigned short* __restrict__ s2u,
                                                   const float* __restrict__ d2,
                                                   const float* __restrict__ side2,
                                                   const float* __restrict__ b2,
                                                   float* __restrict__ out) {
    int wave = threadIdx.x >> 6;
    int lane = threadIdx.x & 63;
    int v = blockIdx.x * 4 + wave;
    if (v >= N) return;
    int c = lane & 15;
    int slot = lane >> 4;
    float dv = d2[v];

    float acc = 0.f, den = 0.f;
    if (slot == 0) {
        float e = bfu2f(s2u[v]) + dv;
        e = fmaxf(e, SLOPE * e);
        float ex = __expf(e);
        acc = ex * bfu2f(h2u[(size_t)v * 16 + c]);
        den = ex;
    }
    int beg = offs[v], end = offs[v + 1];
    int deg = end - beg;
    int ngf = deg >> 3;          // full 8-edge groups: no clamps, no masks
    int rem = deg & 7;
    const int* cb = csr + beg;

    int sA0 = 0, sA1 = 0, sB0 = 0, sB1 = 0;
    float svA0 = 0.f, svA1 = 0.f, hvA0 = 0.f, hvA1 = 0.f;
    float svB0 = 0.f, svB1 = 0.f, hvB0 = 0.f, hvB1 = 0.f;
    if (ngf > 0) {
        sA0 = cb[slot];
        sA1 = cb[4 + slot];
        svA0 = bfu2f(s2u[sA0]);
        svA1 = bfu2f(s2u[sA1]);
        hvA0 = bfu2f(h2u[(size_t)sA0 * 16 + c]);
        hvA1 = bfu2f(h2u[(size_t)sA1 * 16 + c]);
        if (ngf > 1) { sB0 = cb[8 + slot]; sB1 = cb[12 + slot]; }
    }
    int g = 0;
    for (; g + 1 < ngf; g += 2) {
        svB0 = bfu2f(s2u[sB0]);
        svB1 = bfu2f(s2u[sB1]);
        hvB0 = bfu2f(h2u[(size_t)sB0 * 16 + c]);
        hvB1 = bfu2f(h2u[(size_t)sB1 * 16 + c]);
        int sC0 = (g + 2 < ngf) ? cb[(g + 2) * 8 + slot] : 0;
        int sC1 = (g + 2 < ngf) ? cb[(g + 2) * 8 + 4 + slot] : 0;
        {   // group g (A): consumed before reload
            float a0 = svA0 + dv; a0 = fmaxf(a0, SLOPE * a0);
            float a1 = svA1 + dv; a1 = fmaxf(a1, SLOPE * a1);
            float x0 = __expf(a0), x1 = __expf(a1);
            acc += x0 * hvA0 + x1 * hvA1;
            den += x0 + x1;
        }
        sA0 = sC0; sA1 = sC1;
        if (g + 2 < ngf) {
            svA0 = bfu2f(s2u[sA0]);
            svA1 = bfu2f(s2u[sA1]);
            hvA0 = bfu2f(h2u[(size_t)sA0 * 16 + c]);
            hvA1 = bfu2f(h2u[(size_t)sA1 * 16 + c]);
        }
        int sD0 = (g + 3 < ngf) ? cb[(g + 3) * 8 + slot] : 0;
        int sD1 = (g + 3 < ngf) ? cb[(g + 3) * 8 + 4 + slot] : 0;
        {   // group g+1 (B)
            float a0 = svB0 + dv; a0 = fmaxf(a0, SLOPE * a0);
            float a1 = svB1 + dv; a1 = fmaxf(a1, SLOPE * a1);
            float x0 = __expf(a0), x1 = __expf(a1);
            acc += x0 * hvB0 + x1 * hvB1;
            den += x0 + x1;
        }
        sB0 = sD0; sB1 = sD1;
    }
    if (g < ngf) {
        float a0 = svA0 + dv; a0 = fmaxf(a0, SLOPE * a0);
        float a1 = svA1 + dv; a1 = fmaxf(a1, SLOPE * a1);
        float x0 = __expf(a0), x1 = __expf(a1);
        acc += x0 * hvA0 + x1 * hvA1;
        den += x0 + x1;
    }
    if (rem) {   // single masked 8-edge tail group
        int i0 = beg + ngf * 8 + slot;
        int i1 = beg + ngf * 8 + 4 + slot;
        int i0c = i0 < end ? i0 : end - 1;
        int i1c = i1 < end ? i1 : end - 1;
        int s0 = csr[i0c];
        int s1_ = csr[i1c];
        float a0 = bfu2f(s2u[s0]) + dv;  a0 = fmaxf(a0, SLOPE * a0);
        float a1 = bfu2f(s2u[s1_]) + dv; a1 = fmaxf(a1, SLOPE * a1);
        float x0 = __expf(a0), x1 = __expf(a1);
        x0 = (slot < rem) ? x0 : 0.f;
        x1 = (4 + slot < rem) ? x1 : 0.f;
        acc += x0 * bfu2f(h2u[(size_t)s0 * 16 + c]);
        acc += x1 * bfu2f(h2u[(size_t)s1_ * 16 + c]);
        den += x0 + x1;
    }

    acc += __shfl_xor(acc, 16, 64);
    acc += __shfl_xor(acc, 32, 64);
    den += __shfl_xor(den, 16, 64);
    den += __shfl_xor(den, 32, 64);

    float o = acc / den + b2[c];
    float z = o - L2d * side2[(size_t)v * 16 + c];

    float m = z;
#pragma unroll
    for (int off = 1; off < 16; off <<= 1) m = fmaxf(m, __shfl_xor(m, off, 64));
    float ex = __expf(z - m);
    float s = ex;
#pragma unroll
    for (int off = 1; off < 16; off <<= 1) s += __shfl_xor(s, off, 64);
    float lsm = z - m - __logf(s);
    if (slot == 0) out[(size_t)v * 16 + c] = lsm;
}

// ---------------- launch ----------------
extern "C" void kernel_launch(void* const* d_in, const int* in_sizes, int n_in,
                              void* d_out, int out_size, void* d_ws, size_t ws_size,
                              hipStream_t stream) {
    const float* x    = (const float*)d_in[0];
    const int*   ei   = (const int*)d_in[1];
    const float* W1   = (const float*)d_in[2];
    const float* a1s  = (const float*)d_in[3];
    const float* a1d  = (const float*)d_in[4];
    const float* b1   = (const float*)d_in[5];
    const float* W2   = (const float*)d_in[6];
    const float* a2s  = (const float*)d_in[7];
    const float* a2d  = (const float*)d_in[8];
    const float* b2   = (const float*)d_in[9];
    const float* fc1W = (const float*)d_in[10];
    const float* fc1b = (const float*)d_in[11];
    const float* fc2W = (const float*)d_in[12];
    const float* fc2b = (const float*)d_in[13];
    float* out = (float*)d_out;

    int*   wsi = (int*)d_ws;
    float* wsf = (float*)d_ws;
    int*   offs   = wsi + W_OFFS;
    int*   csr    = wsi + W_CSR;
    unsigned int* stage = (unsigned int*)(wsi + W_STAGE);
    int*   bhist  = wsi + W_BHIST;
    int*   tot    = wsi + W_TOT;
    int*   bbase  = wsi + W_BBASE;
    short* h1b    = (short*)(wsf + W_H1B);
    short* s1b    = (short*)(wsf + W_S1B);
    float* d1     = wsf + W_D1;
    float* side1  = wsf + W_SIDE1;
    short* hfb    = (short*)(wsf + W_HFB);
    short* h2b    = (short*)(wsf + W_H2B);
    float* side2  = wsf + W_SIDE2;
    short* s2b    = (short*)(wsf + W_S2B);
    float* d2     = wsf + W_D2;

    // CSR build (no global atomics)
    p1_hist_kernel<<<NBLK, 256, 0, stream>>>(ei, bhist);
    s1_scan_kernel<<<NBUK, 512, 0, stream>>>(bhist, tot);
    s2_scan_kernel<<<1, 512, 0, stream>>>(tot, bbase, offs);
    p2_stage_kernel<<<NBLK, 256, 0, stream>>>(ei, bhist, bbase, stage);
    p3_fine_kernel<<<NBUK, 256, 0, stream>>>(stage, bbase, offs, csr);

    gemm1_kernel<<<(N + 63) / 64, 256, 0, stream>>>(x, W1, fc1W, fc1b, a1s, a1d,
                                                    h1b, side1, s1b, d1);
    agg1_kernel<<<(N + 3) / 4, 256, 0, stream>>>(offs, csr,
                                                 (const unsigned short*)h1b,
                                                 (const unsigned short*)s1b,
                                                 d1, side1, b1, hfb);

    gemm2_kernel<<<(N + 63) / 64, 256, 0, stream>>>((const unsigned short*)hfb,
                                                    W2, fc2W, fc2b, a2s, a2d,
                                                    h2b, side2, s2b, d2);
    agg2_kernel<<<(N + 3) / 4, 256, 0, stream>>>(offs, csr,
                                                 (const unsigned short*)h2b,
                                                 (const unsigned short*)s2b,
                                                 d2, side2, b2, out);
}